// Round 1
// baseline (310.308 us; speedup 1.0000x reference)
//
#include <hip/hip_runtime.h>
#include <math.h>

#define B_ 2
#define L_ 2048
#define D_ 512
#define H_ 8
#define E_ 64
#define CHUNK 32
#define NCH 64                 // L_/CHUNK
#define DEN_EPS_ 1e-5f
#define LN_EPS_ 1e-5f

__device__ __forceinline__ float sigm(float x) { return 1.f / (1.f + expf(-x)); }
__device__ __forceinline__ float elu1(float x) { return x > 0.f ? x + 1.f : expf(x); }

// ---------------------------------------------------------------------------
// Kernel 1: qkv = x @ Wqkv + bqkv, featurize, scatter to Qs/Ks/Vs [B,H,L,E]
// 128x128 tile, 256 threads, 8x8 micro, BK=16
// ---------------------------------------------------------------------------
__global__ __launch_bounds__(256) void k_gemm_qkv(
    const float* __restrict__ X, const float* __restrict__ W,
    const float* __restrict__ bias,
    float* __restrict__ Qs, float* __restrict__ Ks, float* __restrict__ Vs)
{
    __shared__ float As[16][132];
    __shared__ float Bs[16][132];
    const int t  = threadIdx.x;
    const int m0 = blockIdx.y * 128;
    const int n0 = blockIdx.x * 128;
    const int ty = t >> 4, tx = t & 15;

    float c[8][8];
#pragma unroll
    for (int i = 0; i < 8; i++)
#pragma unroll
        for (int j = 0; j < 8; j++) c[i][j] = 0.f;

    for (int k0 = 0; k0 < D_; k0 += 16) {
        {   // A tile: 128 rows x 16 k
            int r = t >> 1, cc = (t & 1) * 8;
            const float* ap = X + (size_t)(m0 + r) * D_ + k0 + cc;
            float4 a0 = *(const float4*)ap;
            float4 a1 = *(const float4*)(ap + 4);
            As[cc + 0][r] = a0.x; As[cc + 1][r] = a0.y;
            As[cc + 2][r] = a0.z; As[cc + 3][r] = a0.w;
            As[cc + 4][r] = a1.x; As[cc + 5][r] = a1.y;
            As[cc + 6][r] = a1.z; As[cc + 7][r] = a1.w;
        }
        {   // B tile: 16 k x 128 n
            int r = t >> 4, cc = (t & 15) * 8;
            const float* bp = W + (size_t)(k0 + r) * 1536 + n0 + cc;
            *(float4*)&Bs[r][cc]     = *(const float4*)bp;
            *(float4*)&Bs[r][cc + 4] = *(const float4*)(bp + 4);
        }
        __syncthreads();
#pragma unroll
        for (int kk = 0; kk < 16; kk++) {
            float a[8], b[8];
            *(float4*)&a[0] = *(float4*)&As[kk][ty * 8];
            *(float4*)&a[4] = *(float4*)&As[kk][ty * 8 + 4];
            *(float4*)&b[0] = *(float4*)&Bs[kk][tx * 8];
            *(float4*)&b[4] = *(float4*)&Bs[kk][tx * 8 + 4];
#pragma unroll
            for (int i = 0; i < 8; i++)
#pragma unroll
                for (int j = 0; j < 8; j++) c[i][j] = fmaf(a[i], b[j], c[i][j]);
        }
        __syncthreads();
    }

    // epilogue: bias + featurize + scatter.  sec uniform per block (n-tile of
    // 128 never crosses a 512 boundary).
    const int sec   = n0 >> 9;
    const int nbase = n0 + tx * 8;
    const int d     = nbase & 511;
    const int h     = d >> 6, e0 = d & 63;
    float* base = (sec == 0 ? Qs : (sec == 1 ? Ks : Vs));
#pragma unroll
    for (int i = 0; i < 8; i++) {
        int m  = m0 + ty * 8 + i;
        int bb = m >> 11, l = m & 2047;
        float out8[8];
#pragma unroll
        for (int j = 0; j < 8; j++) {
            float v = c[i][j] + bias[nbase + j];
            if (sec == 0)      v = elu1(v) * 0.125f;   // q: (elu+1)/sqrt(E)
            else if (sec == 1) v = elu1(v);            // k: elu+1
            out8[j] = v;
        }
        float* dst = base + ((size_t)((bb * H_ + h) * L_ + l)) * E_ + e0;
        *(float4*)dst       = *(float4*)&out8[0];
        *(float4*)(dst + 4) = *(float4*)&out8[4];
    }
}

// ---------------------------------------------------------------------------
// Kernel 2: per (b,h,chunk) G_n[e][f] = sum_i lam^{C-1-i} k_i[e] v_i[f],
//           g_n[e] = sum_i lam^{C-1-i} k_i[e]
// ---------------------------------------------------------------------------
__global__ __launch_bounds__(256) void k_chunk_sums(
    const float* __restrict__ Ks, const float* __restrict__ Vs,
    const float* __restrict__ dl,
    float* __restrict__ Gn, float* __restrict__ gn)
{
    __shared__ float Kw[CHUNK * 68];
    __shared__ float Vv[CHUNK * 64];
    const int t  = threadIdx.x;
    const int bx = blockIdx.x;
    const int n = bx & 63, h = (bx >> 6) & 7, bb = bx >> 9;
    const float lam = sigm(dl[h]);

    {
        int i = t >> 3, e0 = (t & 7) * 8;
        size_t src = ((size_t)(bb * H_ + h) * L_ + n * CHUNK + i) * E_ + e0;
        float w = powf(lam, (float)(CHUNK - 1 - i));
        float4 k0 = *(const float4*)&Ks[src];
        float4 k1 = *(const float4*)&Ks[src + 4];
        k0.x *= w; k0.y *= w; k0.z *= w; k0.w *= w;
        k1.x *= w; k1.y *= w; k1.z *= w; k1.w *= w;
        *(float4*)&Kw[i * 68 + e0]     = k0;
        *(float4*)&Kw[i * 68 + e0 + 4] = k1;
        *(float4*)&Vv[i * 64 + e0]     = *(const float4*)&Vs[src];
        *(float4*)&Vv[i * 64 + e0 + 4] = *(const float4*)&Vs[src + 4];
    }
    __syncthreads();

    const int e = t >> 2, fb = (t & 3) * 16;
    float acc[16];
#pragma unroll
    for (int q = 0; q < 16; q++) acc[q] = 0.f;
#pragma unroll 4
    for (int i = 0; i < CHUNK; i++) {
        float kv = Kw[i * 68 + e];
#pragma unroll
        for (int q = 0; q < 4; q++) {
            float4 v4 = *(float4*)&Vv[i * 64 + fb + q * 4];
            acc[q * 4 + 0] = fmaf(kv, v4.x, acc[q * 4 + 0]);
            acc[q * 4 + 1] = fmaf(kv, v4.y, acc[q * 4 + 1]);
            acc[q * 4 + 2] = fmaf(kv, v4.z, acc[q * 4 + 2]);
            acc[q * 4 + 3] = fmaf(kv, v4.w, acc[q * 4 + 3]);
        }
    }
    size_t gbase = ((size_t)((bb * H_ + h) * NCH + n)) * (E_ * E_) + (size_t)e * E_ + fb;
#pragma unroll
    for (int q = 0; q < 4; q++)
        *(float4*)&Gn[gbase + q * 4] =
            make_float4(acc[q * 4 + 0], acc[q * 4 + 1], acc[q * 4 + 2], acc[q * 4 + 3]);

    if (t < 64) {
        float ga = 0.f;
#pragma unroll 4
        for (int i = 0; i < CHUNK; i++) ga += Kw[i * 68 + t];
        gn[((size_t)((bb * H_ + h) * NCH + n)) * E_ + t] = ga;
    }
}

// ---------------------------------------------------------------------------
// Kernel 3: exclusive prefix scan over chunks: S_{n+1} = lam^C S_n + G_n
// 16 blocks (one per b,h)
// ---------------------------------------------------------------------------
__global__ __launch_bounds__(256) void k_scan(
    const float* __restrict__ Gn, const float* __restrict__ gn,
    const float* __restrict__ dl,
    float* __restrict__ Sp, float* __restrict__ zp)
{
    const int t  = threadIdx.x;
    const int bh = blockIdx.x;            // b*H + h
    const int h  = bh & 7;
    const float lam = sigm(dl[h]);
    const float dC  = powf(lam, (float)CHUNK);

    float4 s[4];
#pragma unroll
    for (int q = 0; q < 4; q++) s[q] = make_float4(0.f, 0.f, 0.f, 0.f);
    float zs = 0.f;

    for (int n = 0; n < NCH; n++) {
        size_t base = ((size_t)bh * NCH + n) * 4096;
#pragma unroll
        for (int q = 0; q < 4; q++) {
            size_t off = base + (size_t)q * 1024 + t * 4;
            *(float4*)&Sp[off] = s[q];
            float4 g = *(const float4*)&Gn[off];
            s[q].x = fmaf(dC, s[q].x, g.x);
            s[q].y = fmaf(dC, s[q].y, g.y);
            s[q].z = fmaf(dC, s[q].z, g.z);
            s[q].w = fmaf(dC, s[q].w, g.w);
        }
        if (t < 64) {
            size_t zo = ((size_t)bh * NCH + n) * E_ + t;
            zp[zo] = zs;
            zs = fmaf(dC, zs, gn[zo]);
        }
    }
}

// ---------------------------------------------------------------------------
// Kernel 4: per (b,h,chunk) output:
//   A[i][j] = (j<=i) ? dot(q_i lam^i, k_j lam^-j) : 0
//   O[i]    = A V + lam * (q_i lam^i) S_n ;  den = rowsum(A) + lam*q~.z + eps
// ---------------------------------------------------------------------------
__global__ __launch_bounds__(256) void k_attn(
    const float* __restrict__ Qs, const float* __restrict__ Ks,
    const float* __restrict__ Vs,
    const float* __restrict__ Sp, const float* __restrict__ zp,
    const float* __restrict__ dl, float* __restrict__ Out)
{
    __shared__ float Qd[CHUNK * 68];
    __shared__ float SK[64 * 68];        // K~ (stride 68) then S (stride 64)
    __shared__ float Vv[CHUNK * 64];
    __shared__ float Am[CHUNK * 33];
    __shared__ float den[CHUNK];
    __shared__ float zz[64];

    const int t  = threadIdx.x;
    const int bx = blockIdx.x;
    const int n = bx & 63, h = (bx >> 6) & 7, bb = bx >> 9;
    const int bh = bb * H_ + h;
    const float lam = sigm(dl[h]);

    {
        int i = t >> 3, e0 = (t & 7) * 8;
        size_t src = ((size_t)bh * L_ + n * CHUNK + i) * E_ + e0;
        float wq = powf(lam, (float)i);
        float wk = powf(lam, -(float)i);
        float4 q0 = *(const float4*)&Qs[src];
        float4 q1 = *(const float4*)&Qs[src + 4];
        q0.x *= wq; q0.y *= wq; q0.z *= wq; q0.w *= wq;
        q1.x *= wq; q1.y *= wq; q1.z *= wq; q1.w *= wq;
        *(float4*)&Qd[i * 68 + e0]     = q0;
        *(float4*)&Qd[i * 68 + e0 + 4] = q1;
        float4 k0 = *(const float4*)&Ks[src];
        float4 k1 = *(const float4*)&Ks[src + 4];
        k0.x *= wk; k0.y *= wk; k0.z *= wk; k0.w *= wk;
        k1.x *= wk; k1.y *= wk; k1.z *= wk; k1.w *= wk;
        *(float4*)&SK[i * 68 + e0]     = k0;
        *(float4*)&SK[i * 68 + e0 + 4] = k1;
        *(float4*)&Vv[i * 64 + e0]     = *(const float4*)&Vs[src];
        *(float4*)&Vv[i * 64 + e0 + 4] = *(const float4*)&Vs[src + 4];
    }
    if (t < 64) zz[t] = zp[((size_t)bh * NCH + n) * E_ + t];
    __syncthreads();

    // Phase A: A = Q~ K~^T with causal mask; row sums -> den (intra part)
    {
        int i = t >> 3, jb = (t & 7) * 4;
        float a[4] = {0.f, 0.f, 0.f, 0.f};
#pragma unroll
        for (int ec = 0; ec < 16; ec++) {
            float4 q4 = *(float4*)&Qd[i * 68 + ec * 4];
#pragma unroll
            for (int jj = 0; jj < 4; jj++) {
                float4 k4 = *(float4*)&SK[(jb + jj) * 68 + ec * 4];
                a[jj] += q4.x * k4.x + q4.y * k4.y + q4.z * k4.z + q4.w * k4.w;
            }
        }
        float r = 0.f;
#pragma unroll
        for (int jj = 0; jj < 4; jj++) {
            if (jb + jj > i) a[jj] = 0.f;
            Am[i * 33 + jb + jj] = a[jj];
            r += a[jj];
        }
        r += __shfl_xor(r, 1);
        r += __shfl_xor(r, 2);
        r += __shfl_xor(r, 4);
        if ((t & 7) == 0) den[i] = r;
    }
    __syncthreads();

    // Load S over K~'s LDS (stride 64); finalize den
    {
        size_t base = ((size_t)bh * NCH + n) * 4096;
#pragma unroll
        for (int q = 0; q < 4; q++)
            *(float4*)&SK[q * 1024 + t * 4] = *(const float4*)&Sp[base + (size_t)q * 1024 + t * 4];
    }
    if (t < CHUNK) {
        float dq = 0.f;
#pragma unroll 8
        for (int e = 0; e < 64; e++) dq += Qd[t * 68 + e] * zz[e];
        den[t] += lam * dq + DEN_EPS_;
    }
    __syncthreads();

    // Phase O
    {
        int i = t >> 3, fb = (t & 7) * 8;
        float o1[8], o2[8];
#pragma unroll
        for (int f = 0; f < 8; f++) { o1[f] = 0.f; o2[f] = 0.f; }
#pragma unroll 4
        for (int j = 0; j < CHUNK; j++) {
            float av = Am[i * 33 + j];
            float4 va = *(float4*)&Vv[j * 64 + fb];
            float4 vb = *(float4*)&Vv[j * 64 + fb + 4];
            o1[0] = fmaf(av, va.x, o1[0]); o1[1] = fmaf(av, va.y, o1[1]);
            o1[2] = fmaf(av, va.z, o1[2]); o1[3] = fmaf(av, va.w, o1[3]);
            o1[4] = fmaf(av, vb.x, o1[4]); o1[5] = fmaf(av, vb.y, o1[5]);
            o1[6] = fmaf(av, vb.z, o1[6]); o1[7] = fmaf(av, vb.w, o1[7]);
        }
#pragma unroll
        for (int ec = 0; ec < 16; ec++) {
            float4 q4 = *(float4*)&Qd[i * 68 + ec * 4];
            float qv[4] = {q4.x, q4.y, q4.z, q4.w};
#pragma unroll
            for (int r = 0; r < 4; r++) {
                int e = ec * 4 + r;
                float4 sa = *(float4*)&SK[e * 64 + fb];
                float4 sb = *(float4*)&SK[e * 64 + fb + 4];
                o2[0] = fmaf(qv[r], sa.x, o2[0]); o2[1] = fmaf(qv[r], sa.y, o2[1]);
                o2[2] = fmaf(qv[r], sa.z, o2[2]); o2[3] = fmaf(qv[r], sa.w, o2[3]);
                o2[4] = fmaf(qv[r], sb.x, o2[4]); o2[5] = fmaf(qv[r], sb.y, o2[5]);
                o2[6] = fmaf(qv[r], sb.z, o2[6]); o2[7] = fmaf(qv[r], sb.w, o2[7]);
            }
        }
        float inv = 1.f / den[i];
        int l = n * CHUNK + i;
        float res[8];
#pragma unroll
        for (int f = 0; f < 8; f++) res[f] = (o1[f] + lam * o2[f]) * inv;
        float* dst = Out + ((size_t)(bb * L_ + l)) * D_ + h * E_ + fb;
        *(float4*)dst       = *(float4*)&res[0];
        *(float4*)(dst + 4) = *(float4*)&res[4];
    }
}

// ---------------------------------------------------------------------------
// Kernel 5: Y = A @ Wout + bout  (written pre-LN into d_out)
// ---------------------------------------------------------------------------
__global__ __launch_bounds__(256) void k_gemm_out(
    const float* __restrict__ A, const float* __restrict__ W,
    const float* __restrict__ bias, float* __restrict__ Y)
{
    __shared__ float As[16][132];
    __shared__ float Bs[16][132];
    const int t  = threadIdx.x;
    const int m0 = blockIdx.y * 128;
    const int n0 = blockIdx.x * 128;
    const int ty = t >> 4, tx = t & 15;

    float c[8][8];
#pragma unroll
    for (int i = 0; i < 8; i++)
#pragma unroll
        for (int j = 0; j < 8; j++) c[i][j] = 0.f;

    for (int k0 = 0; k0 < D_; k0 += 16) {
        {
            int r = t >> 1, cc = (t & 1) * 8;
            const float* ap = A + (size_t)(m0 + r) * D_ + k0 + cc;
            float4 a0 = *(const float4*)ap;
            float4 a1 = *(const float4*)(ap + 4);
            As[cc + 0][r] = a0.x; As[cc + 1][r] = a0.y;
            As[cc + 2][r] = a0.z; As[cc + 3][r] = a0.w;
            As[cc + 4][r] = a1.x; As[cc + 5][r] = a1.y;
            As[cc + 6][r] = a1.z; As[cc + 7][r] = a1.w;
        }
        {
            int r = t >> 4, cc = (t & 15) * 8;
            const float* bp = W + (size_t)(k0 + r) * D_ + n0 + cc;
            *(float4*)&Bs[r][cc]     = *(const float4*)bp;
            *(float4*)&Bs[r][cc + 4] = *(const float4*)(bp + 4);
        }
        __syncthreads();
#pragma unroll
        for (int kk = 0; kk < 16; kk++) {
            float a[8], b[8];
            *(float4*)&a[0] = *(float4*)&As[kk][ty * 8];
            *(float4*)&a[4] = *(float4*)&As[kk][ty * 8 + 4];
            *(float4*)&b[0] = *(float4*)&Bs[kk][tx * 8];
            *(float4*)&b[4] = *(float4*)&Bs[kk][tx * 8 + 4];
#pragma unroll
            for (int i = 0; i < 8; i++)
#pragma unroll
                for (int j = 0; j < 8; j++) c[i][j] = fmaf(a[i], b[j], c[i][j]);
        }
        __syncthreads();
    }
#pragma unroll
    for (int i = 0; i < 8; i++) {
        int m = m0 + ty * 8 + i;
        int nb = n0 + tx * 8;
        float out8[8];
#pragma unroll
        for (int j = 0; j < 8; j++) out8[j] = c[i][j] + bias[nb + j];
        float* dst = Y + (size_t)m * D_ + nb;
        *(float4*)dst       = *(float4*)&out8[0];
        *(float4*)(dst + 4) = *(float4*)&out8[4];
    }
}

// ---------------------------------------------------------------------------
// Kernel 6: in-place LayerNorm over rows of 512
// ---------------------------------------------------------------------------
__global__ __launch_bounds__(256) void k_ln(
    float* __restrict__ Y, const float* __restrict__ gam,
    const float* __restrict__ bet)
{
    __shared__ float red[8];
    const int r = blockIdx.x, t = threadIdx.x;
    float y0 = Y[(size_t)r * 512 + t];
    float y1 = Y[(size_t)r * 512 + 256 + t];
    float s = y0 + y1, sq = y0 * y0 + y1 * y1;
#pragma unroll
    for (int o = 32; o > 0; o >>= 1) {
        s  += __shfl_down(s, o);
        sq += __shfl_down(sq, o);
    }
    int w = t >> 6;
    if ((t & 63) == 0) { red[w] = s; red[4 + w] = sq; }
    __syncthreads();
    if (t == 0) {
        float S  = red[0] + red[1] + red[2] + red[3];
        float SQ = red[4] + red[5] + red[6] + red[7];
        float mu  = S * (1.f / 512.f);
        float var = SQ * (1.f / 512.f) - mu * mu;
        red[0] = mu;
        red[1] = rsqrtf(var + LN_EPS_);
    }
    __syncthreads();
    float mu = red[0], rs = red[1];
    Y[(size_t)r * 512 + t]       = (y0 - mu) * rs * gam[t] + bet[t];
    Y[(size_t)r * 512 + 256 + t] = (y1 - mu) * rs * gam[t + 256] + bet[t + 256];
}

// ---------------------------------------------------------------------------
extern "C" void kernel_launch(void* const* d_in, const int* in_sizes, int n_in,
                              void* d_out, int out_size, void* d_ws, size_t ws_size,
                              hipStream_t stream)
{
    const float* x    = (const float*)d_in[0];
    const float* Wqkv = (const float*)d_in[1];
    const float* bqkv = (const float*)d_in[2];
    const float* Wout = (const float*)d_in[3];
    const float* bout = (const float*)d_in[4];
    const float* gam  = (const float*)d_in[5];
    const float* bet  = (const float*)d_in[6];
    const float* dl   = (const float*)d_in[7];
    float* out = (float*)d_out;

    const size_t NBHLE = (size_t)B_ * H_ * L_ * E_;      // 2,097,152
    const size_t NG    = (size_t)B_ * H_ * NCH * E_ * E_; // 4,194,304
    const size_t Ng    = (size_t)B_ * H_ * NCH * E_;      // 65,536

    float* Qs = (float*)d_ws;
    float* Ks = Qs + NBHLE;
    float* Vs = Ks + NBHLE;
    float* Ao = Vs + NBHLE;                  // attention output [B,L,D]
    float* Gn = Ao + NBHLE;
    float* gn = Gn + NG;
    float* Sp = gn + Ng;
    float* zp = Sp + NG;

    dim3 blk(256);
    k_gemm_qkv  <<<dim3(12, 32),  blk, 0, stream>>>(x, Wqkv, bqkv, Qs, Ks, Vs);
    k_chunk_sums<<<dim3(1024),    blk, 0, stream>>>(Ks, Vs, dl, Gn, gn);
    k_scan      <<<dim3(16),      blk, 0, stream>>>(Gn, gn, dl, Sp, zp);
    k_attn      <<<dim3(1024),    blk, 0, stream>>>(Qs, Ks, Vs, Sp, zp, dl, Ao);
    k_gemm_out  <<<dim3(4, 32),   blk, 0, stream>>>(Ao, Wout, bout, out);
    k_ln        <<<dim3(4096),    blk, 0, stream>>>(out, gam, bet);
}

// Round 2
// 191.076 us; speedup vs baseline: 1.6240x; 1.6240x over previous
//
#include <hip/hip_runtime.h>
#include <math.h>

#define B_ 2
#define L_ 2048
#define D_ 512
#define H_ 8
#define E_ 64
#define CHUNK 32
#define NCH 64                 // L_/CHUNK
#define DEN_EPS_ 1e-5f
#define LN_EPS_ 1e-5f

typedef __bf16 bf16x8 __attribute__((ext_vector_type(8)));
typedef __bf16 bf16x4 __attribute__((ext_vector_type(4)));
typedef float  f32x4  __attribute__((ext_vector_type(4)));

__device__ __forceinline__ float sigm(float x) { return 1.f / (1.f + expf(-x)); }
__device__ __forceinline__ float elu1(float x) { return x > 0.f ? x + 1.f : expf(x); }

// ---------------------------------------------------------------------------
// Conversion: fp32 -> bf16 (straight copy), 8 elems/thread
// ---------------------------------------------------------------------------
__global__ __launch_bounds__(256) void k_conv_x(
    const float* __restrict__ src, __bf16* __restrict__ dst)
{
    int i = (blockIdx.x * 256 + threadIdx.x) * 8;
    float4 a = *(const float4*)&src[i];
    float4 b = *(const float4*)&src[i + 4];
    bf16x8 o;
    o[0] = (__bf16)a.x; o[1] = (__bf16)a.y; o[2] = (__bf16)a.z; o[3] = (__bf16)a.w;
    o[4] = (__bf16)b.x; o[5] = (__bf16)b.y; o[6] = (__bf16)b.z; o[7] = (__bf16)b.w;
    *(bf16x8*)&dst[i] = o;
}

// ---------------------------------------------------------------------------
// Transpose+convert: src fp32 [K][N] -> dst bf16 [N][K]; 64x64 tiles
// ---------------------------------------------------------------------------
__global__ __launch_bounds__(256) void k_transpose_w(
    const float* __restrict__ src, __bf16* __restrict__ dst, int K, int N)
{
    __shared__ __bf16 tile[64][68];
    const int kb = blockIdx.y * 64, nb = blockIdx.x * 64;
    const int t = threadIdx.x;
    const int rr = t >> 4, cc4 = (t & 15) * 4;
#pragma unroll
    for (int p = 0; p < 4; p++) {
        int k = rr + p * 16;
        float4 v = *(const float4*)&src[(size_t)(kb + k) * N + nb + cc4];
        tile[k][cc4 + 0] = (__bf16)v.x;
        tile[k][cc4 + 1] = (__bf16)v.y;
        tile[k][cc4 + 2] = (__bf16)v.z;
        tile[k][cc4 + 3] = (__bf16)v.w;
    }
    __syncthreads();
#pragma unroll
    for (int p = 0; p < 4; p++) {
        int n = rr + p * 16;
        bf16x4 o;
        o[0] = tile[cc4 + 0][n];
        o[1] = tile[cc4 + 1][n];
        o[2] = tile[cc4 + 2][n];
        o[3] = tile[cc4 + 3][n];
        *(bf16x4*)&dst[(size_t)(nb + n) * K + kb + cc4] = o;
    }
}

// ---------------------------------------------------------------------------
// MFMA GEMM 1: qkv = Xb @ WqkvT^T + bias, featurize, scatter Q/K/V [B,H,L,E]
// A bf16 [4096][512], Bt bf16 [1536][512]; 128x128 tile, BK=32, 4 waves 2x2
// ---------------------------------------------------------------------------
__global__ __launch_bounds__(256) void k_mfma_qkv(
    const __bf16* __restrict__ Ab, const __bf16* __restrict__ Bt,
    const float* __restrict__ bias,
    float* __restrict__ Qs, float* __restrict__ Ks, float* __restrict__ Vs)
{
    __shared__ __bf16 Al[128 * 32];
    __shared__ __bf16 Bl[128 * 32];
    const int t = threadIdx.x;
    const int w = t >> 6, lane = t & 63;
    const int wm = w >> 1, wn = w & 1;
    const int ll = lane & 15, quad = lane >> 4;
    const int m0 = blockIdx.y * 128, n0 = blockIdx.x * 128;

    f32x4 acc[4][4] = {};

    const int sr = t >> 2, sk = (t & 3) * 8;     // staging: row, k-offset

    for (int k0 = 0; k0 < D_; k0 += 32) {
        *(bf16x8*)&Al[sr * 32 + sk]        = *(const bf16x8*)&Ab[(size_t)(m0 + sr) * D_ + k0 + sk];
        *(bf16x8*)&Al[(sr + 64) * 32 + sk] = *(const bf16x8*)&Ab[(size_t)(m0 + sr + 64) * D_ + k0 + sk];
        *(bf16x8*)&Bl[sr * 32 + sk]        = *(const bf16x8*)&Bt[(size_t)(n0 + sr) * D_ + k0 + sk];
        *(bf16x8*)&Bl[(sr + 64) * 32 + sk] = *(const bf16x8*)&Bt[(size_t)(n0 + sr + 64) * D_ + k0 + sk];
        __syncthreads();
#pragma unroll
        for (int im = 0; im < 4; im++) {
            bf16x8 a = *(const bf16x8*)&Al[(wm * 64 + im * 16 + ll) * 32 + quad * 8];
#pragma unroll
            for (int in = 0; in < 4; in++) {
                bf16x8 b = *(const bf16x8*)&Bl[(wn * 64 + in * 16 + ll) * 32 + quad * 8];
                acc[im][in] = __builtin_amdgcn_mfma_f32_16x16x32_bf16(a, b, acc[im][in], 0, 0, 0);
            }
        }
        __syncthreads();
    }

    const int sec = n0 >> 9;   // 0:q 1:k 2:v (uniform per block)
    float* base = (sec == 0 ? Qs : (sec == 1 ? Ks : Vs));
#pragma unroll
    for (int im = 0; im < 4; im++) {
#pragma unroll
        for (int in = 0; in < 4; in++) {
            int n = n0 + wn * 64 + in * 16 + ll;
            int d = n & 511, h = d >> 6, e = d & 63;
            float bv = bias[n];
#pragma unroll
            for (int r = 0; r < 4; r++) {
                int m = m0 + wm * 64 + im * 16 + quad * 4 + r;
                int bb = m >> 11, l = m & 2047;
                float v = acc[im][in][r] + bv;
                if (sec == 0)      v = elu1(v) * 0.125f;
                else if (sec == 1) v = elu1(v);
                base[((size_t)((bb * H_ + h) * L_ + l)) * E_ + e] = v;
            }
        }
    }
}

// ---------------------------------------------------------------------------
// MFMA GEMM 2: Y = Ao @ WoutT^T + bout  (pre-LN, into d_out)
// ---------------------------------------------------------------------------
__global__ __launch_bounds__(256) void k_mfma_out(
    const __bf16* __restrict__ Ab, const __bf16* __restrict__ Bt,
    const float* __restrict__ bias, float* __restrict__ Y)
{
    __shared__ __bf16 Al[128 * 32];
    __shared__ __bf16 Bl[128 * 32];
    const int t = threadIdx.x;
    const int w = t >> 6, lane = t & 63;
    const int wm = w >> 1, wn = w & 1;
    const int ll = lane & 15, quad = lane >> 4;
    const int m0 = blockIdx.y * 128, n0 = blockIdx.x * 128;

    f32x4 acc[4][4] = {};
    const int sr = t >> 2, sk = (t & 3) * 8;

    for (int k0 = 0; k0 < D_; k0 += 32) {
        *(bf16x8*)&Al[sr * 32 + sk]        = *(const bf16x8*)&Ab[(size_t)(m0 + sr) * D_ + k0 + sk];
        *(bf16x8*)&Al[(sr + 64) * 32 + sk] = *(const bf16x8*)&Ab[(size_t)(m0 + sr + 64) * D_ + k0 + sk];
        *(bf16x8*)&Bl[sr * 32 + sk]        = *(const bf16x8*)&Bt[(size_t)(n0 + sr) * D_ + k0 + sk];
        *(bf16x8*)&Bl[(sr + 64) * 32 + sk] = *(const bf16x8*)&Bt[(size_t)(n0 + sr + 64) * D_ + k0 + sk];
        __syncthreads();
#pragma unroll
        for (int im = 0; im < 4; im++) {
            bf16x8 a = *(const bf16x8*)&Al[(wm * 64 + im * 16 + ll) * 32 + quad * 8];
#pragma unroll
            for (int in = 0; in < 4; in++) {
                bf16x8 b = *(const bf16x8*)&Bl[(wn * 64 + in * 16 + ll) * 32 + quad * 8];
                acc[im][in] = __builtin_amdgcn_mfma_f32_16x16x32_bf16(a, b, acc[im][in], 0, 0, 0);
            }
        }
        __syncthreads();
    }
#pragma unroll
    for (int im = 0; im < 4; im++) {
#pragma unroll
        for (int in = 0; in < 4; in++) {
            int n = n0 + wn * 64 + in * 16 + ll;
            float bv = bias[n];
#pragma unroll
            for (int r = 0; r < 4; r++) {
                int m = m0 + wm * 64 + im * 16 + quad * 4 + r;
                Y[(size_t)m * D_ + n] = acc[im][in][r] + bv;
            }
        }
    }
}

// ---------------------------------------------------------------------------
// Kernel 2: per (b,h,chunk) G_n[e][f] = sum_i lam^{C-1-i} k_i[e] v_i[f],
//           g_n[e] = sum_i lam^{C-1-i} k_i[e]
// ---------------------------------------------------------------------------
__global__ __launch_bounds__(256) void k_chunk_sums(
    const float* __restrict__ Ks, const float* __restrict__ Vs,
    const float* __restrict__ dl,
    float* __restrict__ Gn, float* __restrict__ gn)
{
    __shared__ float Kw[CHUNK * 68];
    __shared__ float Vv[CHUNK * 64];
    const int t  = threadIdx.x;
    const int bx = blockIdx.x;
    const int n = bx & 63, h = (bx >> 6) & 7, bb = bx >> 9;
    const float lam = sigm(dl[h]);

    {
        int i = t >> 3, e0 = (t & 7) * 8;
        size_t src = ((size_t)(bb * H_ + h) * L_ + n * CHUNK + i) * E_ + e0;
        float w = powf(lam, (float)(CHUNK - 1 - i));
        float4 k0 = *(const float4*)&Ks[src];
        float4 k1 = *(const float4*)&Ks[src + 4];
        k0.x *= w; k0.y *= w; k0.z *= w; k0.w *= w;
        k1.x *= w; k1.y *= w; k1.z *= w; k1.w *= w;
        *(float4*)&Kw[i * 68 + e0]     = k0;
        *(float4*)&Kw[i * 68 + e0 + 4] = k1;
        *(float4*)&Vv[i * 64 + e0]     = *(const float4*)&Vs[src];
        *(float4*)&Vv[i * 64 + e0 + 4] = *(const float4*)&Vs[src + 4];
    }
    __syncthreads();

    const int e = t >> 2, fb = (t & 3) * 16;
    float acc[16];
#pragma unroll
    for (int q = 0; q < 16; q++) acc[q] = 0.f;
#pragma unroll 4
    for (int i = 0; i < CHUNK; i++) {
        float kv = Kw[i * 68 + e];
#pragma unroll
        for (int q = 0; q < 4; q++) {
            float4 v4 = *(float4*)&Vv[i * 64 + fb + q * 4];
            acc[q * 4 + 0] = fmaf(kv, v4.x, acc[q * 4 + 0]);
            acc[q * 4 + 1] = fmaf(kv, v4.y, acc[q * 4 + 1]);
            acc[q * 4 + 2] = fmaf(kv, v4.z, acc[q * 4 + 2]);
            acc[q * 4 + 3] = fmaf(kv, v4.w, acc[q * 4 + 3]);
        }
    }
    size_t gbase = ((size_t)((bb * H_ + h) * NCH + n)) * (E_ * E_) + (size_t)e * E_ + fb;
#pragma unroll
    for (int q = 0; q < 4; q++)
        *(float4*)&Gn[gbase + q * 4] =
            make_float4(acc[q * 4 + 0], acc[q * 4 + 1], acc[q * 4 + 2], acc[q * 4 + 3]);

    if (t < 64) {
        float ga = 0.f;
#pragma unroll 4
        for (int i = 0; i < CHUNK; i++) ga += Kw[i * 68 + t];
        gn[((size_t)((bb * H_ + h) * NCH + n)) * E_ + t] = ga;
    }
}

// ---------------------------------------------------------------------------
// Kernel 3: exclusive prefix scan over chunks: S_{n+1} = lam^C S_n + G_n
// ---------------------------------------------------------------------------
__global__ __launch_bounds__(256) void k_scan(
    const float* __restrict__ Gn, const float* __restrict__ gn,
    const float* __restrict__ dl,
    float* __restrict__ Sp, float* __restrict__ zp)
{
    const int t  = threadIdx.x;
    const int bh = blockIdx.x;            // b*H + h
    const int h  = bh & 7;
    const float lam = sigm(dl[h]);
    const float dC  = powf(lam, (float)CHUNK);

    float4 s[4];
#pragma unroll
    for (int q = 0; q < 4; q++) s[q] = make_float4(0.f, 0.f, 0.f, 0.f);
    float zs = 0.f;

    for (int n = 0; n < NCH; n++) {
        size_t base = ((size_t)bh * NCH + n) * 4096;
#pragma unroll
        for (int q = 0; q < 4; q++) {
            size_t off = base + (size_t)q * 1024 + t * 4;
            *(float4*)&Sp[off] = s[q];
            float4 g = *(const float4*)&Gn[off];
            s[q].x = fmaf(dC, s[q].x, g.x);
            s[q].y = fmaf(dC, s[q].y, g.y);
            s[q].z = fmaf(dC, s[q].z, g.z);
            s[q].w = fmaf(dC, s[q].w, g.w);
        }
        if (t < 64) {
            size_t zo = ((size_t)bh * NCH + n) * E_ + t;
            zp[zo] = zs;
            zs = fmaf(dC, zs, gn[zo]);
        }
    }
}

// ---------------------------------------------------------------------------
// Kernel 4: per (b,h,chunk) attention output -> Ao (bf16 [B*L][D])
// ---------------------------------------------------------------------------
__global__ __launch_bounds__(256) void k_attn(
    const float* __restrict__ Qs, const float* __restrict__ Ks,
    const float* __restrict__ Vs,
    const float* __restrict__ Sp, const float* __restrict__ zp,
    const float* __restrict__ dl, __bf16* __restrict__ Out)
{
    __shared__ float Qd[CHUNK * 68];
    __shared__ float SK[64 * 68];        // K~ (stride 68) then S (stride 64)
    __shared__ float Vv[CHUNK * 64];
    __shared__ float Am[CHUNK * 33];
    __shared__ float den[CHUNK];
    __shared__ float zz[64];

    const int t  = threadIdx.x;
    const int bx = blockIdx.x;
    const int n = bx & 63, h = (bx >> 6) & 7, bb = bx >> 9;
    const int bh = bb * H_ + h;
    const float lam = sigm(dl[h]);

    {
        int i = t >> 3, e0 = (t & 7) * 8;
        size_t src = ((size_t)bh * L_ + n * CHUNK + i) * E_ + e0;
        float wq = powf(lam, (float)i);
        float wk = powf(lam, -(float)i);
        float4 q0 = *(const float4*)&Qs[src];
        float4 q1 = *(const float4*)&Qs[src + 4];
        q0.x *= wq; q0.y *= wq; q0.z *= wq; q0.w *= wq;
        q1.x *= wq; q1.y *= wq; q1.z *= wq; q1.w *= wq;
        *(float4*)&Qd[i * 68 + e0]     = q0;
        *(float4*)&Qd[i * 68 + e0 + 4] = q1;
        float4 k0 = *(const float4*)&Ks[src];
        float4 k1 = *(const float4*)&Ks[src + 4];
        k0.x *= wk; k0.y *= wk; k0.z *= wk; k0.w *= wk;
        k1.x *= wk; k1.y *= wk; k1.z *= wk; k1.w *= wk;
        *(float4*)&SK[i * 68 + e0]     = k0;
        *(float4*)&SK[i * 68 + e0 + 4] = k1;
        *(float4*)&Vv[i * 64 + e0]     = *(const float4*)&Vs[src];
        *(float4*)&Vv[i * 64 + e0 + 4] = *(const float4*)&Vs[src + 4];
    }
    if (t < 64) zz[t] = zp[((size_t)bh * NCH + n) * E_ + t];
    __syncthreads();

    // Phase A: A = Q~ K~^T with causal mask; row sums -> den (intra part)
    {
        int i = t >> 3, jb = (t & 7) * 4;
        float a[4] = {0.f, 0.f, 0.f, 0.f};
#pragma unroll
        for (int ec = 0; ec < 16; ec++) {
            float4 q4 = *(float4*)&Qd[i * 68 + ec * 4];
#pragma unroll
            for (int jj = 0; jj < 4; jj++) {
                float4 k4 = *(float4*)&SK[(jb + jj) * 68 + ec * 4];
                a[jj] += q4.x * k4.x + q4.y * k4.y + q4.z * k4.z + q4.w * k4.w;
            }
        }
        float r = 0.f;
#pragma unroll
        for (int jj = 0; jj < 4; jj++) {
            if (jb + jj > i) a[jj] = 0.f;
            Am[i * 33 + jb + jj] = a[jj];
            r += a[jj];
        }
        r += __shfl_xor(r, 1);
        r += __shfl_xor(r, 2);
        r += __shfl_xor(r, 4);
        if ((t & 7) == 0) den[i] = r;
    }
    __syncthreads();

    // Load S over K~'s LDS (stride 64); finalize den
    {
        size_t base = ((size_t)bh * NCH + n) * 4096;
#pragma unroll
        for (int q = 0; q < 4; q++)
            *(float4*)&SK[q * 1024 + t * 4] = *(const float4*)&Sp[base + (size_t)q * 1024 + t * 4];
    }
    if (t < CHUNK) {
        float dq = 0.f;
#pragma unroll 8
        for (int e = 0; e < 64; e++) dq += Qd[t * 68 + e] * zz[e];
        den[t] += lam * dq + DEN_EPS_;
    }
    __syncthreads();

    // Phase O
    {
        int i = t >> 3, fb = (t & 7) * 8;
        float o1[8], o2[8];
#pragma unroll
        for (int f = 0; f < 8; f++) { o1[f] = 0.f; o2[f] = 0.f; }
#pragma unroll 4
        for (int j = 0; j < CHUNK; j++) {
            float av = Am[i * 33 + j];
            float4 va = *(float4*)&Vv[j * 64 + fb];
            float4 vb = *(float4*)&Vv[j * 64 + fb + 4];
            o1[0] = fmaf(av, va.x, o1[0]); o1[1] = fmaf(av, va.y, o1[1]);
            o1[2] = fmaf(av, va.z, o1[2]); o1[3] = fmaf(av, va.w, o1[3]);
            o1[4] = fmaf(av, vb.x, o1[4]); o1[5] = fmaf(av, vb.y, o1[5]);
            o1[6] = fmaf(av, vb.z, o1[6]); o1[7] = fmaf(av, vb.w, o1[7]);
        }
#pragma unroll
        for (int ec = 0; ec < 16; ec++) {
            float4 q4 = *(float4*)&Qd[i * 68 + ec * 4];
            float qv[4] = {q4.x, q4.y, q4.z, q4.w};
#pragma unroll
            for (int r = 0; r < 4; r++) {
                int e = ec * 4 + r;
                float4 sa = *(float4*)&SK[e * 64 + fb];
                float4 sb = *(float4*)&SK[e * 64 + fb + 4];
                o2[0] = fmaf(qv[r], sa.x, o2[0]); o2[1] = fmaf(qv[r], sa.y, o2[1]);
                o2[2] = fmaf(qv[r], sa.z, o2[2]); o2[3] = fmaf(qv[r], sa.w, o2[3]);
                o2[4] = fmaf(qv[r], sb.x, o2[4]); o2[5] = fmaf(qv[r], sb.y, o2[5]);
                o2[6] = fmaf(qv[r], sb.z, o2[6]); o2[7] = fmaf(qv[r], sb.w, o2[7]);
            }
        }
        float inv = 1.f / den[i];
        int l = n * CHUNK + i;
        bf16x8 ov;
#pragma unroll
        for (int f = 0; f < 8; f++) ov[f] = (__bf16)((o1[f] + lam * o2[f]) * inv);
        *(bf16x8*)&Out[((size_t)(bb * L_ + l)) * D_ + h * E_ + fb] = ov;
    }
}

// ---------------------------------------------------------------------------
// Kernel 6: in-place LayerNorm over rows of 512
// ---------------------------------------------------------------------------
__global__ __launch_bounds__(256) void k_ln(
    float* __restrict__ Y, const float* __restrict__ gam,
    const float* __restrict__ bet)
{
    __shared__ float red[8];
    const int r = blockIdx.x, t = threadIdx.x;
    float y0 = Y[(size_t)r * 512 + t];
    float y1 = Y[(size_t)r * 512 + 256 + t];
    float s = y0 + y1, sq = y0 * y0 + y1 * y1;
#pragma unroll
    for (int o = 32; o > 0; o >>= 1) {
        s  += __shfl_down(s, o);
        sq += __shfl_down(sq, o);
    }
    int w = t >> 6;
    if ((t & 63) == 0) { red[w] = s; red[4 + w] = sq; }
    __syncthreads();
    if (t == 0) {
        float S  = red[0] + red[1] + red[2] + red[3];
        float SQ = red[4] + red[5] + red[6] + red[7];
        float mu  = S * (1.f / 512.f);
        float var = SQ * (1.f / 512.f) - mu * mu;
        red[0] = mu;
        red[1] = rsqrtf(var + LN_EPS_);
    }
    __syncthreads();
    float mu = red[0], rs = red[1];
    Y[(size_t)r * 512 + t]       = (y0 - mu) * rs * gam[t] + bet[t];
    Y[(size_t)r * 512 + 256 + t] = (y1 - mu) * rs * gam[t + 256] + bet[t + 256];
}

// ---------------------------------------------------------------------------
extern "C" void kernel_launch(void* const* d_in, const int* in_sizes, int n_in,
                              void* d_out, int out_size, void* d_ws, size_t ws_size,
                              hipStream_t stream)
{
    const float* x    = (const float*)d_in[0];
    const float* Wqkv = (const float*)d_in[1];
    const float* bqkv = (const float*)d_in[2];
    const float* Wout = (const float*)d_in[3];
    const float* bout = (const float*)d_in[4];
    const float* gam  = (const float*)d_in[5];
    const float* bet  = (const float*)d_in[6];
    const float* dl   = (const float*)d_in[7];
    float* out = (float*)d_out;

    const size_t NBHLE = (size_t)B_ * H_ * L_ * E_;       // 2,097,152
    const size_t NG    = (size_t)B_ * H_ * NCH * E_ * E_; // 4,194,304
    const size_t Ng    = (size_t)B_ * H_ * NCH * E_;      // 65,536

    char* p = (char*)d_ws;
    float* Qs = (float*)p;            p += NBHLE * 4;
    float* Ks = (float*)p;            p += NBHLE * 4;
    float* Vs = (float*)p;            p += NBHLE * 4;
    float* Gn = (float*)p;            p += NG * 4;
    float* gn = (float*)p;            p += Ng * 4;
    float* Sp = (float*)p;            p += NG * 4;
    float* zp = (float*)p;            p += Ng * 4;
    __bf16* Xb    = (__bf16*)p;       p += NBHLE * 2;          // [4096][512]
    __bf16* WqkvT = (__bf16*)p;       p += (size_t)1536 * 512 * 2;
    __bf16* WoutT = (__bf16*)p;       p += (size_t)512 * 512 * 2;
    __bf16* Ao    = (__bf16*)p;       p += NBHLE * 2;          // [4096][512]

    dim3 blk(256);
    k_conv_x     <<<dim3(1024),   blk, 0, stream>>>(x, Xb);
    k_transpose_w<<<dim3(24, 8),  blk, 0, stream>>>(Wqkv, WqkvT, 512, 1536);
    k_transpose_w<<<dim3(8, 8),   blk, 0, stream>>>(Wout, WoutT, 512, 512);
    k_mfma_qkv   <<<dim3(12, 32), blk, 0, stream>>>(Xb, WqkvT, bqkv, Qs, Ks, Vs);
    k_chunk_sums <<<dim3(1024),   blk, 0, stream>>>(Ks, Vs, dl, Gn, gn);
    k_scan       <<<dim3(16),     blk, 0, stream>>>(Gn, gn, dl, Sp, zp);
    k_attn       <<<dim3(1024),   blk, 0, stream>>>(Qs, Ks, Vs, Sp, zp, dl, Ao);
    k_mfma_out   <<<dim3(4, 32),  blk, 0, stream>>>(Ao, WoutT, bout, out);
    k_ln         <<<dim3(4096),   blk, 0, stream>>>(out, gam, bet);
}

// Round 3
// 169.304 us; speedup vs baseline: 1.8328x; 1.1286x over previous
//
#include <hip/hip_runtime.h>
#include <math.h>

#define B_ 2
#define L_ 2048
#define D_ 512
#define H_ 8
#define E_ 64
#define CHUNK 32
#define NCH 64                 // L_/CHUNK
#define DEN_EPS_ 1e-5f
#define LN_EPS_ 1e-5f

typedef __bf16 bf16x8 __attribute__((ext_vector_type(8)));
typedef __bf16 bf16x4 __attribute__((ext_vector_type(4)));
typedef float  f32x4  __attribute__((ext_vector_type(4)));

__device__ __forceinline__ float sigm(float x) { return 1.f / (1.f + expf(-x)); }
__device__ __forceinline__ float elu1(float x) { return x > 0.f ? x + 1.f : expf(x); }

// ---------------------------------------------------------------------------
// fp32 -> bf16 copy
// ---------------------------------------------------------------------------
__global__ __launch_bounds__(256) void k_conv_x(
    const float* __restrict__ src, __bf16* __restrict__ dst)
{
    int i = (blockIdx.x * 256 + threadIdx.x) * 8;
    float4 a = *(const float4*)&src[i];
    float4 b = *(const float4*)&src[i + 4];
    bf16x8 o;
    o[0] = (__bf16)a.x; o[1] = (__bf16)a.y; o[2] = (__bf16)a.z; o[3] = (__bf16)a.w;
    o[4] = (__bf16)b.x; o[5] = (__bf16)b.y; o[6] = (__bf16)b.z; o[7] = (__bf16)b.w;
    *(bf16x8*)&dst[i] = o;
}

// ---------------------------------------------------------------------------
// Transpose+convert: src fp32 [K][N] -> dst bf16 [N][K]; 64x64 tiles
// ---------------------------------------------------------------------------
__global__ __launch_bounds__(256) void k_transpose_w(
    const float* __restrict__ src, __bf16* __restrict__ dst, int K, int N)
{
    __shared__ __bf16 tile[64][68];
    const int kb = blockIdx.y * 64, nb = blockIdx.x * 64;
    const int t = threadIdx.x;
    const int rr = t >> 4, cc4 = (t & 15) * 4;
#pragma unroll
    for (int p = 0; p < 4; p++) {
        int k = rr + p * 16;
        float4 v = *(const float4*)&src[(size_t)(kb + k) * N + nb + cc4];
        tile[k][cc4 + 0] = (__bf16)v.x;
        tile[k][cc4 + 1] = (__bf16)v.y;
        tile[k][cc4 + 2] = (__bf16)v.z;
        tile[k][cc4 + 3] = (__bf16)v.w;
    }
    __syncthreads();
#pragma unroll
    for (int p = 0; p < 4; p++) {
        int n = rr + p * 16;
        bf16x4 o;
        o[0] = tile[cc4 + 0][n];
        o[1] = tile[cc4 + 1][n];
        o[2] = tile[cc4 + 2][n];
        o[3] = tile[cc4 + 3][n];
        *(bf16x4*)&dst[(size_t)(nb + n) * K + kb + cc4] = o;
    }
}

// ---------------------------------------------------------------------------
// MFMA GEMM 1: qkv = Xb @ WqkvT^T + bias, featurize, scatter bf16 Q/K/V
// [B,H,L,E].  128x128 tile, BK=32, 4 waves 2x2
// ---------------------------------------------------------------------------
__global__ __launch_bounds__(256) void k_mfma_qkv(
    const __bf16* __restrict__ Ab, const __bf16* __restrict__ Bt,
    const float* __restrict__ bias,
    __bf16* __restrict__ Qb, __bf16* __restrict__ Kb, __bf16* __restrict__ Vb)
{
    __shared__ __bf16 Al[128 * 32];
    __shared__ __bf16 Bl[128 * 32];
    const int t = threadIdx.x;
    const int w = t >> 6, lane = t & 63;
    const int wm = w >> 1, wn = w & 1;
    const int ll = lane & 15, quad = lane >> 4;
    const int m0 = blockIdx.y * 128, n0 = blockIdx.x * 128;

    f32x4 acc[4][4] = {};
    const int sr = t >> 2, sk = (t & 3) * 8;

    for (int k0 = 0; k0 < D_; k0 += 32) {
        *(bf16x8*)&Al[sr * 32 + sk]        = *(const bf16x8*)&Ab[(size_t)(m0 + sr) * D_ + k0 + sk];
        *(bf16x8*)&Al[(sr + 64) * 32 + sk] = *(const bf16x8*)&Ab[(size_t)(m0 + sr + 64) * D_ + k0 + sk];
        *(bf16x8*)&Bl[sr * 32 + sk]        = *(const bf16x8*)&Bt[(size_t)(n0 + sr) * D_ + k0 + sk];
        *(bf16x8*)&Bl[(sr + 64) * 32 + sk] = *(const bf16x8*)&Bt[(size_t)(n0 + sr + 64) * D_ + k0 + sk];
        __syncthreads();
#pragma unroll
        for (int im = 0; im < 4; im++) {
            bf16x8 a = *(const bf16x8*)&Al[(wm * 64 + im * 16 + ll) * 32 + quad * 8];
#pragma unroll
            for (int in = 0; in < 4; in++) {
                bf16x8 b = *(const bf16x8*)&Bl[(wn * 64 + in * 16 + ll) * 32 + quad * 8];
                acc[im][in] = __builtin_amdgcn_mfma_f32_16x16x32_bf16(a, b, acc[im][in], 0, 0, 0);
            }
        }
        __syncthreads();
    }

    const int sec = n0 >> 9;   // 0:q 1:k 2:v (uniform per block)
    __bf16* base = (sec == 0 ? Qb : (sec == 1 ? Kb : Vb));
#pragma unroll
    for (int im = 0; im < 4; im++) {
#pragma unroll
        for (int in = 0; in < 4; in++) {
            int n = n0 + wn * 64 + in * 16 + ll;
            int d = n & 511, h = d >> 6, e = d & 63;
            float bv = bias[n];
#pragma unroll
            for (int r = 0; r < 4; r++) {
                int m = m0 + wm * 64 + im * 16 + quad * 4 + r;
                int bb = m >> 11, l = m & 2047;
                float v = acc[im][in][r] + bv;
                if (sec == 0)      v = elu1(v) * 0.125f;
                else if (sec == 1) v = elu1(v);
                base[((size_t)((bb * H_ + h) * L_ + l)) * E_ + e] = (__bf16)v;
            }
        }
    }
}

// ---------------------------------------------------------------------------
// MFMA GEMM 2: Y = Ao @ WoutT^T + bout  (pre-LN, into d_out)
// ---------------------------------------------------------------------------
__global__ __launch_bounds__(256) void k_mfma_out(
    const __bf16* __restrict__ Ab, const __bf16* __restrict__ Bt,
    const float* __restrict__ bias, float* __restrict__ Y)
{
    __shared__ __bf16 Al[128 * 32];
    __shared__ __bf16 Bl[128 * 32];
    const int t = threadIdx.x;
    const int w = t >> 6, lane = t & 63;
    const int wm = w >> 1, wn = w & 1;
    const int ll = lane & 15, quad = lane >> 4;
    const int m0 = blockIdx.y * 128, n0 = blockIdx.x * 128;

    f32x4 acc[4][4] = {};
    const int sr = t >> 2, sk = (t & 3) * 8;

    for (int k0 = 0; k0 < D_; k0 += 32) {
        *(bf16x8*)&Al[sr * 32 + sk]        = *(const bf16x8*)&Ab[(size_t)(m0 + sr) * D_ + k0 + sk];
        *(bf16x8*)&Al[(sr + 64) * 32 + sk] = *(const bf16x8*)&Ab[(size_t)(m0 + sr + 64) * D_ + k0 + sk];
        *(bf16x8*)&Bl[sr * 32 + sk]        = *(const bf16x8*)&Bt[(size_t)(n0 + sr) * D_ + k0 + sk];
        *(bf16x8*)&Bl[(sr + 64) * 32 + sk] = *(const bf16x8*)&Bt[(size_t)(n0 + sr + 64) * D_ + k0 + sk];
        __syncthreads();
#pragma unroll
        for (int im = 0; im < 4; im++) {
            bf16x8 a = *(const bf16x8*)&Al[(wm * 64 + im * 16 + ll) * 32 + quad * 8];
#pragma unroll
            for (int in = 0; in < 4; in++) {
                bf16x8 b = *(const bf16x8*)&Bl[(wn * 64 + in * 16 + ll) * 32 + quad * 8];
                acc[im][in] = __builtin_amdgcn_mfma_f32_16x16x32_bf16(a, b, acc[im][in], 0, 0, 0);
            }
        }
        __syncthreads();
    }
#pragma unroll
    for (int im = 0; im < 4; im++) {
#pragma unroll
        for (int in = 0; in < 4; in++) {
            int n = n0 + wn * 64 + in * 16 + ll;
            float bv = bias[n];
#pragma unroll
            for (int r = 0; r < 4; r++) {
                int m = m0 + wm * 64 + im * 16 + quad * 4 + r;
                Y[(size_t)m * D_ + n] = acc[im][in][r] + bv;
            }
        }
    }
}

// ---------------------------------------------------------------------------
// Chunk sums (MFMA): per (b,h,n)  G_n = K_w^T V  (64x64, K=32),
//                    g_n[e] = sum_i K_w[i][e];  K_w = K~ * lam^(C-1-i)
// ---------------------------------------------------------------------------
__global__ __launch_bounds__(256) void k_chunk_g(
    const __bf16* __restrict__ Kb, const __bf16* __restrict__ Vb,
    const float* __restrict__ dl,
    float* __restrict__ Gn, float* __restrict__ gn)
{
    __shared__ __bf16 Kwt[64][40];   // [e][i], weighted
    __shared__ __bf16 Vt[64][40];    // [f][i]
    const int t  = threadIdx.x;
    const int bx = blockIdx.x;
    const int n = bx & 63, h = (bx >> 6) & 7, bb = bx >> 9;
    const int bh = bb * H_ + h;
    const float lam = sigm(dl[h]);

    {   // stage transposed
        int i = t & 31, e0 = (t >> 5) * 8;
        size_t src = ((size_t)bh * L_ + n * CHUNK + i) * E_ + e0;
        float wk = powf(lam, (float)(CHUNK - 1 - i));
        bf16x8 k8 = *(const bf16x8*)&Kb[src];
        bf16x8 v8 = *(const bf16x8*)&Vb[src];
#pragma unroll
        for (int q = 0; q < 8; q++) {
            Kwt[e0 + q][i] = (__bf16)((float)k8[q] * wk);
            Vt[e0 + q][i]  = v8[q];
        }
    }
    __syncthreads();

    const int w = t >> 6, lane = t & 63;
    const int wm = w >> 1, wn = w & 1;
    const int ll = lane & 15, quad = lane >> 4;

    bf16x8 af[2], bf_[2];
#pragma unroll
    for (int a = 0; a < 2; a++) {
        af[a]  = *(const bf16x8*)&Kwt[wm * 32 + a * 16 + ll][quad * 8];
        bf_[a] = *(const bf16x8*)&Vt[wn * 32 + a * 16 + ll][quad * 8];
    }
    f32x4 acc[2][2] = {};
#pragma unroll
    for (int a = 0; a < 2; a++)
#pragma unroll
        for (int b = 0; b < 2; b++)
            acc[a][b] = __builtin_amdgcn_mfma_f32_16x16x32_bf16(af[a], bf_[b], acc[a][b], 0, 0, 0);

    size_t gbase = ((size_t)bh * NCH + n) * 4096;
#pragma unroll
    for (int a = 0; a < 2; a++)
#pragma unroll
        for (int b = 0; b < 2; b++)
#pragma unroll
            for (int r = 0; r < 4; r++) {
                int e = wm * 32 + a * 16 + quad * 4 + r;
                int f = wn * 32 + b * 16 + ll;
                Gn[gbase + (size_t)e * 64 + f] = acc[a][b][r];
            }

    if (t < 64) {
        float ga = 0.f;
#pragma unroll
        for (int k8 = 0; k8 < 4; k8++) {
            bf16x8 kk = *(const bf16x8*)&Kwt[t][k8 * 8];
#pragma unroll
            for (int q = 0; q < 8; q++) ga += (float)kk[q];
        }
        gn[((size_t)bh * NCH + n) * E_ + t] = ga;
    }
}

// ---------------------------------------------------------------------------
// Parallel scan: one wave per (bh, e-row).  S_{n+1} = lam^C S_n + G_n
// ---------------------------------------------------------------------------
__global__ __launch_bounds__(64) void k_scan_par(
    const float* __restrict__ Gn, const float* __restrict__ gn,
    const float* __restrict__ dl,
    float* __restrict__ Sp, float* __restrict__ zp)
{
    const int t  = threadIdx.x;
    const int bh = blockIdx.x >> 6;
    const int e  = blockIdx.x & 63;
    const int h  = bh & 7;
    const float lam = sigm(dl[h]);
    const float dC  = powf(lam, (float)CHUNK);

    float s = 0.f, zs = 0.f;
    for (int n = 0; n < NCH; n++) {
        size_t off = (((size_t)bh * NCH + n) * 64 + e) * 64 + t;
        Sp[off] = s;
        float g = Gn[off];
        if (t == 0) {
            size_t zo = ((size_t)bh * NCH + n) * E_ + e;
            zp[zo] = zs;
            zs = fmaf(dC, zs, gn[zo]);
        }
        s = fmaf(dC, s, g);
    }
}

// ---------------------------------------------------------------------------
// Attention (MFMA): per (b,h,n):
//   A = Qw Kw^T (masked j<=i);  O = A V + Qw (lam S);  den = rowsum(A)+lam Qw.z
// ---------------------------------------------------------------------------
__global__ __launch_bounds__(256) void k_attn(
    const __bf16* __restrict__ Qb, const __bf16* __restrict__ Kb,
    const __bf16* __restrict__ Vb,
    const float* __restrict__ Sp, const float* __restrict__ zp,
    const float* __restrict__ dl, __bf16* __restrict__ Out)
{
    __shared__ __bf16 Qw[32][64];
    __shared__ __bf16 Kw[32][64];
    __shared__ __bf16 Vt[64][40];
    __shared__ float  Sf[64 * 65];
    __shared__ __bf16 A1[32][40];
    __shared__ float  den[32];
    __shared__ float  zz[64];

    const int t  = threadIdx.x;
    const int bx = blockIdx.x;
    const int n = bx & 63, h = (bx >> 6) & 7, bb = bx >> 9;
    const int bh = bb * H_ + h;
    const float lam = sigm(dl[h]);

    {   // stage Q,K (weighted, natural), V (transposed), S (fp32), z
        int i = t >> 3, e0 = (t & 7) * 8;
        size_t src = ((size_t)bh * L_ + n * CHUNK + i) * E_ + e0;
        float wq = powf(lam, (float)i);
        float wk = powf(lam, -(float)i);
        bf16x8 q8 = *(const bf16x8*)&Qb[src];
        bf16x8 k8 = *(const bf16x8*)&Kb[src];
        bf16x8 v8 = *(const bf16x8*)&Vb[src];
        bf16x8 qo, ko;
#pragma unroll
        for (int q = 0; q < 8; q++) {
            qo[q] = (__bf16)((float)q8[q] * wq);
            ko[q] = (__bf16)((float)k8[q] * wk);
            Vt[e0 + q][i] = v8[q];
        }
        *(bf16x8*)&Qw[i][e0] = qo;
        *(bf16x8*)&Kw[i][e0] = ko;

        size_t sbase = ((size_t)bh * NCH + n) * 4096;
#pragma unroll
        for (int p = 0; p < 4; p++) {
            int lin = p * 256 + t;
            int e = lin >> 4, f4 = (lin & 15) * 4;
            float4 g = *(const float4*)&Sp[sbase + (size_t)e * 64 + f4];
            Sf[e * 65 + f4 + 0] = g.x;
            Sf[e * 65 + f4 + 1] = g.y;
            Sf[e * 65 + f4 + 2] = g.z;
            Sf[e * 65 + f4 + 3] = g.w;
        }
        if (t < 64) zz[t] = zp[((size_t)bh * NCH + n) * E_ + t];
    }
    __syncthreads();

    const int w = t >> 6, lane = t & 63;
    const int ll = lane & 15, quad = lane >> 4;

    // Phase A: each wave one 16x16 tile of the 32x32 A
    {
        const int wm = w >> 1, wn = w & 1;
        f32x4 accA = {};
#pragma unroll
        for (int ks = 0; ks < 2; ks++) {
            bf16x8 a = *(const bf16x8*)&Qw[wm * 16 + ll][ks * 32 + quad * 8];
            bf16x8 b = *(const bf16x8*)&Kw[wn * 16 + ll][ks * 32 + quad * 8];
            accA = __builtin_amdgcn_mfma_f32_16x16x32_bf16(a, b, accA, 0, 0, 0);
        }
        int j = wn * 16 + ll;
#pragma unroll
        for (int r = 0; r < 4; r++) {
            int i = wm * 16 + quad * 4 + r;
            A1[i][j] = (__bf16)(j <= i ? accA[r] : 0.f);
        }
    }
    __syncthreads();

    // den (one wave's worth of threads)
    if (t < 32) {
        float rs = 0.f;
#pragma unroll
        for (int k8 = 0; k8 < 4; k8++) {
            bf16x8 aa = *(const bf16x8*)&A1[t][k8 * 8];
#pragma unroll
            for (int q = 0; q < 8; q++) rs += (float)aa[q];
        }
        float qz = 0.f;
#pragma unroll
        for (int e8 = 0; e8 < 8; e8++) {
            bf16x8 qq = *(const bf16x8*)&Qw[t][e8 * 8];
#pragma unroll
            for (int q = 0; q < 8; q++) qz += (float)qq[q] * zz[e8 * 8 + q];
        }
        den[t] = rs + lam * qz + DEN_EPS_;
    }

    // Phase O: wave w owns f-range [w*16, w*16+16)
    const int f0 = w * 16;
    f32x4 acc1[2] = {}, acc2[2] = {};
    {
        bf16x8 bV = *(const bf16x8*)&Vt[f0 + ll][quad * 8];
#pragma unroll
        for (int im = 0; im < 2; im++) {
            bf16x8 aA = *(const bf16x8*)&A1[im * 16 + ll][quad * 8];
            acc1[im] = __builtin_amdgcn_mfma_f32_16x16x32_bf16(aA, bV, acc1[im], 0, 0, 0);
        }
#pragma unroll
        for (int ks = 0; ks < 2; ks++) {
            bf16x8 bS;
#pragma unroll
            for (int jj = 0; jj < 8; jj++)
                bS[jj] = (__bf16)(lam * Sf[(ks * 32 + quad * 8 + jj) * 65 + f0 + ll]);
#pragma unroll
            for (int im = 0; im < 2; im++) {
                bf16x8 aQ = *(const bf16x8*)&Qw[im * 16 + ll][ks * 32 + quad * 8];
                acc2[im] = __builtin_amdgcn_mfma_f32_16x16x32_bf16(aQ, bS, acc2[im], 0, 0, 0);
            }
        }
    }
    __syncthreads();

#pragma unroll
    for (int im = 0; im < 2; im++)
#pragma unroll
        for (int r = 0; r < 4; r++) {
            int i = im * 16 + quad * 4 + r;
            float o = (acc1[im][r] + acc2[im][r]) / den[i];
            Out[((size_t)bb * L_ + n * CHUNK + i) * D_ + h * E_ + f0 + ll] = (__bf16)o;
        }
}

// ---------------------------------------------------------------------------
// LayerNorm over rows of 512 (in-place on d_out)
// ---------------------------------------------------------------------------
__global__ __launch_bounds__(256) void k_ln(
    float* __restrict__ Y, const float* __restrict__ gam,
    const float* __restrict__ bet)
{
    __shared__ float red[8];
    const int r = blockIdx.x, t = threadIdx.x;
    float y0 = Y[(size_t)r * 512 + t];
    float y1 = Y[(size_t)r * 512 + 256 + t];
    float s = y0 + y1, sq = y0 * y0 + y1 * y1;
#pragma unroll
    for (int o = 32; o > 0; o >>= 1) {
        s  += __shfl_down(s, o);
        sq += __shfl_down(sq, o);
    }
    int w = t >> 6;
    if ((t & 63) == 0) { red[w] = s; red[4 + w] = sq; }
    __syncthreads();
    if (t == 0) {
        float S  = red[0] + red[1] + red[2] + red[3];
        float SQ = red[4] + red[5] + red[6] + red[7];
        float mu  = S * (1.f / 512.f);
        float var = SQ * (1.f / 512.f) - mu * mu;
        red[0] = mu;
        red[1] = rsqrtf(var + LN_EPS_);
    }
    __syncthreads();
    float mu = red[0], rs = red[1];
    Y[(size_t)r * 512 + t]       = (y0 - mu) * rs * gam[t] + bet[t];
    Y[(size_t)r * 512 + 256 + t] = (y1 - mu) * rs * gam[t + 256] + bet[t + 256];
}

// ---------------------------------------------------------------------------
extern "C" void kernel_launch(void* const* d_in, const int* in_sizes, int n_in,
                              void* d_out, int out_size, void* d_ws, size_t ws_size,
                              hipStream_t stream)
{
    const float* x    = (const float*)d_in[0];
    const float* Wqkv = (const float*)d_in[1];
    const float* bqkv = (const float*)d_in[2];
    const float* Wout = (const float*)d_in[3];
    const float* bout = (const float*)d_in[4];
    const float* gam  = (const float*)d_in[5];
    const float* bet  = (const float*)d_in[6];
    const float* dl   = (const float*)d_in[7];
    float* out = (float*)d_out;

    const size_t NBHLE = (size_t)B_ * H_ * L_ * E_;       // 2,097,152
    const size_t NG    = (size_t)B_ * H_ * NCH * E_ * E_; // 4,194,304
    const size_t Ng    = (size_t)B_ * H_ * NCH * E_;      // 65,536

    char* p = (char*)d_ws;
    float*  Gn = (float*)p;      p += NG * 4;
    float*  Sp = (float*)p;      p += NG * 4;
    float*  gn = (float*)p;      p += Ng * 4;
    float*  zp = (float*)p;      p += Ng * 4;
    __bf16* Qb = (__bf16*)p;     p += NBHLE * 2;
    __bf16* Kb = (__bf16*)p;     p += NBHLE * 2;
    __bf16* Vb = (__bf16*)p;     p += NBHLE * 2;
    __bf16* Xb    = (__bf16*)p;  p += NBHLE * 2;               // [4096][512]
    __bf16* WqkvT = (__bf16*)p;  p += (size_t)1536 * 512 * 2;
    __bf16* WoutT = (__bf16*)p;  p += (size_t)512 * 512 * 2;
    __bf16* Ao    = (__bf16*)p;  p += NBHLE * 2;               // [4096][512]

    dim3 blk(256);
    k_conv_x     <<<dim3(1024),   blk, 0, stream>>>(x, Xb);
    k_transpose_w<<<dim3(24, 8),  blk, 0, stream>>>(Wqkv, WqkvT, 512, 1536);
    k_transpose_w<<<dim3(8, 8),   blk, 0, stream>>>(Wout, WoutT, 512, 512);
    k_mfma_qkv   <<<dim3(12, 32), blk, 0, stream>>>(Xb, WqkvT, bqkv, Qb, Kb, Vb);
    k_chunk_g    <<<dim3(1024),   blk, 0, stream>>>(Kb, Vb, dl, Gn, gn);
    k_scan_par   <<<dim3(1024),   dim3(64), 0, stream>>>(Gn, gn, dl, Sp, zp);
    k_attn       <<<dim3(1024),   blk, 0, stream>>>(Qb, Kb, Vb, Sp, zp, dl, Ao);
    k_mfma_out   <<<dim3(4, 32),  blk, 0, stream>>>(Ao, WoutT, bout, out);
    k_ln         <<<dim3(4096),   blk, 0, stream>>>(out, gam, bet);
}

// Round 4
// 157.998 us; speedup vs baseline: 1.9640x; 1.0716x over previous
//
#include <hip/hip_runtime.h>
#include <math.h>

#define B_ 2
#define L_ 2048
#define D_ 512
#define H_ 8
#define E_ 64
#define CHUNK 32
#define NCH 64                 // L_/CHUNK
#define DEN_EPS_ 1e-5f
#define LN_EPS_ 1e-5f

typedef __bf16 bf16x8 __attribute__((ext_vector_type(8)));
typedef __bf16 bf16x4 __attribute__((ext_vector_type(4)));
typedef float  f32x4  __attribute__((ext_vector_type(4)));

__device__ __forceinline__ float sigm(float x) { return 1.f / (1.f + expf(-x)); }
__device__ __forceinline__ float elu1(float x) { return x > 0.f ? x + 1.f : expf(x); }

// ---------------------------------------------------------------------------
// Both weight transposes in one launch: fp32 [K][N] -> bf16 [N][K]
// z=0: Wqkv (512x1536), z=1: Wout (512x512, blocks x>=8 idle)
// ---------------------------------------------------------------------------
__global__ __launch_bounds__(256) void k_transpose_both(
    const float* __restrict__ W1, __bf16* __restrict__ D1,
    const float* __restrict__ W2, __bf16* __restrict__ D2)
{
    const float* src; __bf16* dst; int N;
    if (blockIdx.z == 0) { src = W1; dst = D1; N = 1536; }
    else                 { if (blockIdx.x >= 8) return; src = W2; dst = D2; N = 512; }
    const int K = 512;

    __shared__ __bf16 tile[64][68];
    const int kb = blockIdx.y * 64, nb = blockIdx.x * 64;
    const int t = threadIdx.x;
    const int rr = t >> 4, cc4 = (t & 15) * 4;
#pragma unroll
    for (int p = 0; p < 4; p++) {
        int k = rr + p * 16;
        float4 v = *(const float4*)&src[(size_t)(kb + k) * N + nb + cc4];
        tile[k][cc4 + 0] = (__bf16)v.x;
        tile[k][cc4 + 1] = (__bf16)v.y;
        tile[k][cc4 + 2] = (__bf16)v.z;
        tile[k][cc4 + 3] = (__bf16)v.w;
    }
    __syncthreads();
#pragma unroll
    for (int p = 0; p < 4; p++) {
        int n = rr + p * 16;
        bf16x4 o;
        o[0] = tile[cc4 + 0][n];
        o[1] = tile[cc4 + 1][n];
        o[2] = tile[cc4 + 2][n];
        o[3] = tile[cc4 + 3][n];
        *(bf16x4*)&dst[(size_t)(nb + n) * K + kb + cc4] = o;
    }
}

// ---------------------------------------------------------------------------
// MFMA GEMM 1: qkv = x @ WqkvT^T + bias  (x fp32, converted during staging),
// featurize, scatter bf16 Q/K/V [B,H,L,E].  128x128 tile, BK=32, 4 waves 2x2
// ---------------------------------------------------------------------------
__global__ __launch_bounds__(256) void k_mfma_qkv(
    const float* __restrict__ X, const __bf16* __restrict__ Bt,
    const float* __restrict__ bias,
    __bf16* __restrict__ Qb, __bf16* __restrict__ Kb, __bf16* __restrict__ Vb)
{
    __shared__ __bf16 Al[128 * 32];
    __shared__ __bf16 Bl[128 * 32];
    const int t = threadIdx.x;
    const int w = t >> 6, lane = t & 63;
    const int wm = w >> 1, wn = w & 1;
    const int ll = lane & 15, quad = lane >> 4;
    const int m0 = blockIdx.y * 128, n0 = blockIdx.x * 128;

    f32x4 acc[4][4] = {};
    const int sr = t >> 2, sk = (t & 3) * 8;

    for (int k0 = 0; k0 < D_; k0 += 32) {
#pragma unroll
        for (int half = 0; half < 2; half++) {
            const float* ap = X + (size_t)(m0 + sr + half * 64) * D_ + k0 + sk;
            float4 a0 = *(const float4*)ap;
            float4 a1 = *(const float4*)(ap + 4);
            bf16x8 o;
            o[0] = (__bf16)a0.x; o[1] = (__bf16)a0.y; o[2] = (__bf16)a0.z; o[3] = (__bf16)a0.w;
            o[4] = (__bf16)a1.x; o[5] = (__bf16)a1.y; o[6] = (__bf16)a1.z; o[7] = (__bf16)a1.w;
            *(bf16x8*)&Al[(sr + half * 64) * 32 + sk] = o;
        }
        *(bf16x8*)&Bl[sr * 32 + sk]        = *(const bf16x8*)&Bt[(size_t)(n0 + sr) * D_ + k0 + sk];
        *(bf16x8*)&Bl[(sr + 64) * 32 + sk] = *(const bf16x8*)&Bt[(size_t)(n0 + sr + 64) * D_ + k0 + sk];
        __syncthreads();
#pragma unroll
        for (int im = 0; im < 4; im++) {
            bf16x8 a = *(const bf16x8*)&Al[(wm * 64 + im * 16 + ll) * 32 + quad * 8];
#pragma unroll
            for (int in = 0; in < 4; in++) {
                bf16x8 b = *(const bf16x8*)&Bl[(wn * 64 + in * 16 + ll) * 32 + quad * 8];
                acc[im][in] = __builtin_amdgcn_mfma_f32_16x16x32_bf16(a, b, acc[im][in], 0, 0, 0);
            }
        }
        __syncthreads();
    }

    const int sec = n0 >> 9;   // 0:q 1:k 2:v (uniform per block)
    __bf16* base = (sec == 0 ? Qb : (sec == 1 ? Kb : Vb));
#pragma unroll
    for (int im = 0; im < 4; im++) {
#pragma unroll
        for (int in = 0; in < 4; in++) {
            int n = n0 + wn * 64 + in * 16 + ll;
            int d = n & 511, h = d >> 6, e = d & 63;
            float bv = bias[n];
#pragma unroll
            for (int r = 0; r < 4; r++) {
                int m = m0 + wm * 64 + im * 16 + quad * 4 + r;
                int bb = m >> 11, l = m & 2047;
                float v = acc[im][in][r] + bv;
                if (sec == 0)      v = elu1(v) * 0.125f;
                else if (sec == 1) v = elu1(v);
                base[((size_t)((bb * H_ + h) * L_ + l)) * E_ + e] = (__bf16)v;
            }
        }
    }
}

// ---------------------------------------------------------------------------
// Chunk sums (MFMA): per (b,h,n)  G_n = K_w^T V (64x64, K=32) -> bf16,
//                    g_n[e] = sum_i K_w[i][e] -> fp32
// ---------------------------------------------------------------------------
__global__ __launch_bounds__(256) void k_chunk_g(
    const __bf16* __restrict__ Kb, const __bf16* __restrict__ Vb,
    const float* __restrict__ dl,
    __bf16* __restrict__ Gnb, float* __restrict__ gn)
{
    __shared__ __bf16 Kwt[64][40];   // [e][i], weighted
    __shared__ __bf16 Vt[64][40];    // [f][i]
    const int t  = threadIdx.x;
    const int bx = blockIdx.x;
    const int n = bx & 63, h = (bx >> 6) & 7, bb = bx >> 9;
    const int bh = bb * H_ + h;
    const float lam = sigm(dl[h]);

    {   // stage transposed
        int i = t & 31, e0 = (t >> 5) * 8;
        size_t src = ((size_t)bh * L_ + n * CHUNK + i) * E_ + e0;
        float wk = powf(lam, (float)(CHUNK - 1 - i));
        bf16x8 k8 = *(const bf16x8*)&Kb[src];
        bf16x8 v8 = *(const bf16x8*)&Vb[src];
#pragma unroll
        for (int q = 0; q < 8; q++) {
            Kwt[e0 + q][i] = (__bf16)((float)k8[q] * wk);
            Vt[e0 + q][i]  = v8[q];
        }
    }
    __syncthreads();

    const int w = t >> 6, lane = t & 63;
    const int wm = w >> 1, wn = w & 1;
    const int ll = lane & 15, quad = lane >> 4;

    bf16x8 af[2], bf_[2];
#pragma unroll
    for (int a = 0; a < 2; a++) {
        af[a]  = *(const bf16x8*)&Kwt[wm * 32 + a * 16 + ll][quad * 8];
        bf_[a] = *(const bf16x8*)&Vt[wn * 32 + a * 16 + ll][quad * 8];
    }
    f32x4 acc[2][2] = {};
#pragma unroll
    for (int a = 0; a < 2; a++)
#pragma unroll
        for (int b = 0; b < 2; b++)
            acc[a][b] = __builtin_amdgcn_mfma_f32_16x16x32_bf16(af[a], bf_[b], acc[a][b], 0, 0, 0);

    size_t gbase = ((size_t)bh * NCH + n) * 4096;
#pragma unroll
    for (int a = 0; a < 2; a++)
#pragma unroll
        for (int b = 0; b < 2; b++)
#pragma unroll
            for (int r = 0; r < 4; r++) {
                int e = wm * 32 + a * 16 + quad * 4 + r;
                int f = wn * 32 + b * 16 + ll;
                Gnb[gbase + (size_t)e * 64 + f] = (__bf16)acc[a][b][r];
            }

    if (t < 64) {
        float ga = 0.f;
#pragma unroll
        for (int k8 = 0; k8 < 4; k8++) {
            bf16x8 kk = *(const bf16x8*)&Kwt[t][k8 * 8];
#pragma unroll
            for (int q = 0; q < 8; q++) ga += (float)kk[q];
        }
        gn[((size_t)bh * NCH + n) * E_ + t] = ga;
    }
}

// ---------------------------------------------------------------------------
// Parallel scan: one wave per (bh, e-row).  S_{n+1} = lam^C S_n + G_n.
// Emits exclusive-prefix lam*S (bf16) and lam*z (fp32).  Prefetched loop.
// ---------------------------------------------------------------------------
__global__ __launch_bounds__(64) void k_scan_par(
    const __bf16* __restrict__ Gnb, const float* __restrict__ gn,
    const float* __restrict__ dl,
    __bf16* __restrict__ Sb, float* __restrict__ zl)
{
    const int t  = threadIdx.x;
    const int bh = blockIdx.x >> 6;
    const int e  = blockIdx.x & 63;
    const float lam = sigm(dl[bh & 7]);
    const float dC  = powf(lam, (float)CHUNK);

    float s = 0.f, zs = 0.f;
    const size_t base = ((size_t)bh * NCH) * 4096 + (size_t)e * 64 + t;
    float g = (float)Gnb[base];
    for (int n = 0; n < NCH; n++) {
        size_t off = base + (size_t)n * 4096;
        float gnext = (n < NCH - 1) ? (float)Gnb[off + 4096] : 0.f;
        Sb[off] = (__bf16)(lam * s);
        s = fmaf(dC, s, g);
        g = gnext;
        if (t == 0) {
            size_t zo = ((size_t)bh * NCH + n) * E_ + e;
            zl[zo] = lam * zs;
            zs = fmaf(dC, zs, gn[zo]);
        }
    }
}

// ---------------------------------------------------------------------------
// Attention (MFMA): per (b,h,n):
//   A = Qw Kw^T (masked);  O = A V + Qw SbT;  den = rowsum(A) + Qw.zz + eps
//   (Sb/zz already carry the lam factor from the scan)
// ---------------------------------------------------------------------------
__global__ __launch_bounds__(256) void k_attn(
    const __bf16* __restrict__ Qb, const __bf16* __restrict__ Kb,
    const __bf16* __restrict__ Vb,
    const __bf16* __restrict__ Sb, const float* __restrict__ zl,
    const float* __restrict__ dl, __bf16* __restrict__ Out)
{
    __shared__ __bf16 Qw[32][64];
    __shared__ __bf16 Kw[32][64];
    __shared__ __bf16 Vt[64][40];
    __shared__ __bf16 SbT[64][72];   // [f][e]
    __shared__ __bf16 A1[32][40];
    __shared__ float  den[32];
    __shared__ float  zz[64];

    const int t  = threadIdx.x;
    const int bx = blockIdx.x;
    const int n = bx & 63, h = (bx >> 6) & 7, bb = bx >> 9;
    const int bh = bb * H_ + h;
    const float lam = sigm(dl[h]);

    {   // stage Q,K (weighted), V (transposed)
        int i = t >> 3, e0 = (t & 7) * 8;
        size_t src = ((size_t)bh * L_ + n * CHUNK + i) * E_ + e0;
        float wq = powf(lam, (float)i);
        float wk = powf(lam, -(float)i);
        bf16x8 q8 = *(const bf16x8*)&Qb[src];
        bf16x8 k8 = *(const bf16x8*)&Kb[src];
        bf16x8 v8 = *(const bf16x8*)&Vb[src];
        bf16x8 qo, ko;
#pragma unroll
        for (int q = 0; q < 8; q++) {
            qo[q] = (__bf16)((float)q8[q] * wq);
            ko[q] = (__bf16)((float)k8[q] * wk);
            Vt[e0 + q][i] = v8[q];
        }
        *(bf16x8*)&Qw[i][e0] = qo;
        *(bf16x8*)&Kw[i][e0] = ko;

        // stage S (lam-scaled, bf16) transposed -> SbT[f][e]
        int e = t >> 2, f0 = (t & 3) * 16;
        size_t sbase = ((size_t)bh * NCH + n) * 4096;
        bf16x8 s0 = *(const bf16x8*)&Sb[sbase + (size_t)e * 64 + f0];
        bf16x8 s1 = *(const bf16x8*)&Sb[sbase + (size_t)e * 64 + f0 + 8];
#pragma unroll
        for (int q = 0; q < 8; q++) {
            SbT[f0 + q][e]     = s0[q];
            SbT[f0 + 8 + q][e] = s1[q];
        }
        if (t < 64) zz[t] = zl[((size_t)bh * NCH + n) * E_ + t];
    }
    __syncthreads();

    const int w = t >> 6, lane = t & 63;
    const int ll = lane & 15, quad = lane >> 4;

    // Phase A: each wave one 16x16 tile of the 32x32 A
    {
        const int wm = w >> 1, wn = w & 1;
        f32x4 accA = {};
#pragma unroll
        for (int ks = 0; ks < 2; ks++) {
            bf16x8 a = *(const bf16x8*)&Qw[wm * 16 + ll][ks * 32 + quad * 8];
            bf16x8 b = *(const bf16x8*)&Kw[wn * 16 + ll][ks * 32 + quad * 8];
            accA = __builtin_amdgcn_mfma_f32_16x16x32_bf16(a, b, accA, 0, 0, 0);
        }
        int j = wn * 16 + ll;
#pragma unroll
        for (int r = 0; r < 4; r++) {
            int i = wm * 16 + quad * 4 + r;
            A1[i][j] = (__bf16)(j <= i ? accA[r] : 0.f);
        }
    }
    __syncthreads();

    // den
    if (t < 32) {
        float rs = 0.f;
#pragma unroll
        for (int k8 = 0; k8 < 4; k8++) {
            bf16x8 aa = *(const bf16x8*)&A1[t][k8 * 8];
#pragma unroll
            for (int q = 0; q < 8; q++) rs += (float)aa[q];
        }
        float qz = 0.f;
#pragma unroll
        for (int e8 = 0; e8 < 8; e8++) {
            bf16x8 qq = *(const bf16x8*)&Qw[t][e8 * 8];
#pragma unroll
            for (int q = 0; q < 8; q++) qz += (float)qq[q] * zz[e8 * 8 + q];
        }
        den[t] = rs + qz + DEN_EPS_;
    }

    // Phase O: wave w owns f-range [w*16, w*16+16)
    const int fw = w * 16;
    f32x4 acc1[2] = {}, acc2[2] = {};
    {
        bf16x8 bV = *(const bf16x8*)&Vt[fw + ll][quad * 8];
#pragma unroll
        for (int im = 0; im < 2; im++) {
            bf16x8 aA = *(const bf16x8*)&A1[im * 16 + ll][quad * 8];
            acc1[im] = __builtin_amdgcn_mfma_f32_16x16x32_bf16(aA, bV, acc1[im], 0, 0, 0);
        }
#pragma unroll
        for (int ks = 0; ks < 2; ks++) {
            bf16x8 bS = *(const bf16x8*)&SbT[fw + ll][ks * 32 + quad * 8];
#pragma unroll
            for (int im = 0; im < 2; im++) {
                bf16x8 aQ = *(const bf16x8*)&Qw[im * 16 + ll][ks * 32 + quad * 8];
                acc2[im] = __builtin_amdgcn_mfma_f32_16x16x32_bf16(aQ, bS, acc2[im], 0, 0, 0);
            }
        }
    }
    __syncthreads();

#pragma unroll
    for (int im = 0; im < 2; im++)
#pragma unroll
        for (int r = 0; r < 4; r++) {
            int i = im * 16 + quad * 4 + r;
            float o = (acc1[im][r] + acc2[im][r]) / den[i];
            Out[((size_t)bb * L_ + n * CHUNK + i) * D_ + h * E_ + fw + ll] = (__bf16)o;
        }
}

// ---------------------------------------------------------------------------
// MFMA GEMM 2 + fused LayerNorm: Y = LN(Ao @ WoutT^T + bout)
// Tile 32 rows x 512 cols (full rows); 4 waves split N; row stats from regs.
// ---------------------------------------------------------------------------
__global__ __launch_bounds__(256) void k_mfma_out_ln(
    const __bf16* __restrict__ Ab, const __bf16* __restrict__ Bt,
    const float* __restrict__ bias, const float* __restrict__ gam,
    const float* __restrict__ bet, float* __restrict__ Y)
{
    __shared__ __bf16 Al[32 * 32];
    __shared__ __bf16 Bl[512 * 32];
    __shared__ float gaml[512], betl[512], bl[512];
    __shared__ float redS[4][32], redQ[4][32];
    __shared__ float mv[32][2];

    const int t = threadIdx.x;
    const int w = t >> 6, lane = t & 63;
    const int ll = lane & 15, quad = lane >> 4;
    const int m0 = blockIdx.x * 32;

    {   // preload per-column params
        float2 g = *(const float2*)&gam[t * 2];
        float2 b2 = *(const float2*)&bet[t * 2];
        float2 bo = *(const float2*)&bias[t * 2];
        gaml[t * 2] = g.x;  gaml[t * 2 + 1] = g.y;
        betl[t * 2] = b2.x; betl[t * 2 + 1] = b2.y;
        bl[t * 2]   = bo.x; bl[t * 2 + 1]   = bo.y;
    }

    f32x4 acc[2][8] = {};
    const int sr = t >> 2, sk = (t & 3) * 8;

    for (int k0 = 0; k0 < D_; k0 += 32) {
        if (t < 128)
            *(bf16x8*)&Al[sr * 32 + sk] = *(const bf16x8*)&Ab[(size_t)(m0 + sr) * D_ + k0 + sk];
#pragma unroll
        for (int p = 0; p < 8; p++)
            *(bf16x8*)&Bl[(sr + p * 64) * 32 + sk] =
                *(const bf16x8*)&Bt[(size_t)(sr + p * 64) * D_ + k0 + sk];
        __syncthreads();
#pragma unroll
        for (int im = 0; im < 2; im++) {
            bf16x8 a = *(const bf16x8*)&Al[(im * 16 + ll) * 32 + quad * 8];
#pragma unroll
            for (int in = 0; in < 8; in++) {
                bf16x8 b = *(const bf16x8*)&Bl[(w * 128 + in * 16 + ll) * 32 + quad * 8];
                acc[im][in] = __builtin_amdgcn_mfma_f32_16x16x32_bf16(a, b, acc[im][in], 0, 0, 0);
            }
        }
        __syncthreads();
    }

    // bias + row-stat partials from registers
    float vals[2][8][4];
    float ps[2][4] = {}, pq[2][4] = {};
#pragma unroll
    for (int im = 0; im < 2; im++)
#pragma unroll
        for (int in = 0; in < 8; in++) {
            int col = w * 128 + in * 16 + ll;
            float bv = bl[col];
#pragma unroll
            for (int r = 0; r < 4; r++) {
                float v = acc[im][in][r] + bv;
                vals[im][in][r] = v;
                ps[im][r] += v;
                pq[im][r] += v * v;
            }
        }
#pragma unroll
    for (int im = 0; im < 2; im++)
#pragma unroll
        for (int r = 0; r < 4; r++) {
            float s = ps[im][r], q = pq[im][r];
            s += __shfl_xor(s, 1); q += __shfl_xor(q, 1);
            s += __shfl_xor(s, 2); q += __shfl_xor(q, 2);
            s += __shfl_xor(s, 4); q += __shfl_xor(q, 4);
            s += __shfl_xor(s, 8); q += __shfl_xor(q, 8);
            if (ll == 0) {
                int row = im * 16 + quad * 4 + r;
                redS[w][row] = s;
                redQ[w][row] = q;
            }
        }
    __syncthreads();
    if (t < 32) {
        float S = redS[0][t] + redS[1][t] + redS[2][t] + redS[3][t];
        float Q = redQ[0][t] + redQ[1][t] + redQ[2][t] + redQ[3][t];
        float mu  = S * (1.f / 512.f);
        float var = Q * (1.f / 512.f) - mu * mu;
        mv[t][0] = mu;
        mv[t][1] = rsqrtf(var + LN_EPS_);
    }
    __syncthreads();
#pragma unroll
    for (int im = 0; im < 2; im++)
#pragma unroll
        for (int r = 0; r < 4; r++) {
            int row = im * 16 + quad * 4 + r;
            float mu = mv[row][0], rs = mv[row][1];
#pragma unroll
            for (int in = 0; in < 8; in++) {
                int col = w * 128 + in * 16 + ll;
                Y[(size_t)(m0 + row) * D_ + col] =
                    (vals[im][in][r] - mu) * rs * gaml[col] + betl[col];
            }
        }
}

// ---------------------------------------------------------------------------
extern "C" void kernel_launch(void* const* d_in, const int* in_sizes, int n_in,
                              void* d_out, int out_size, void* d_ws, size_t ws_size,
                              hipStream_t stream)
{
    const float* x    = (const float*)d_in[0];
    const float* Wqkv = (const float*)d_in[1];
    const float* bqkv = (const float*)d_in[2];
    const float* Wout = (const float*)d_in[3];
    const float* bout = (const float*)d_in[4];
    const float* gam  = (const float*)d_in[5];
    const float* bet  = (const float*)d_in[6];
    const float* dl   = (const float*)d_in[7];
    float* out = (float*)d_out;

    const size_t NBHLE = (size_t)B_ * H_ * L_ * E_;       // 2,097,152
    const size_t NG    = (size_t)B_ * H_ * NCH * E_ * E_; // 4,194,304
    const size_t Ng    = (size_t)B_ * H_ * NCH * E_;      // 65,536

    char* p = (char*)d_ws;
    __bf16* Gnb = (__bf16*)p;    p += NG * 2;
    __bf16* Sb  = (__bf16*)p;    p += NG * 2;
    float*  gn  = (float*)p;     p += Ng * 4;
    float*  zl  = (float*)p;     p += Ng * 4;
    __bf16* Qb  = (__bf16*)p;    p += NBHLE * 2;
    __bf16* Kb  = (__bf16*)p;    p += NBHLE * 2;
    __bf16* Vb  = (__bf16*)p;    p += NBHLE * 2;
    __bf16* WqkvT = (__bf16*)p;  p += (size_t)1536 * 512 * 2;
    __bf16* WoutT = (__bf16*)p;  p += (size_t)512 * 512 * 2;
    __bf16* Ao    = (__bf16*)p;  p += NBHLE * 2;               // [4096][512]

    dim3 blk(256);
    k_transpose_both<<<dim3(24, 8, 2), blk, 0, stream>>>(Wqkv, WqkvT, Wout, WoutT);
    k_mfma_qkv      <<<dim3(12, 32),   blk, 0, stream>>>(x, WqkvT, bqkv, Qb, Kb, Vb);
    k_chunk_g       <<<dim3(1024),     blk, 0, stream>>>(Kb, Vb, dl, Gnb, gn);
    k_scan_par      <<<dim3(1024),     dim3(64), 0, stream>>>(Gnb, gn, dl, Sb, zl);
    k_attn          <<<dim3(1024),     blk, 0, stream>>>(Qb, Kb, Vb, Sb, zl, dl, Ao);
    k_mfma_out_ln   <<<dim3(128),      blk, 0, stream>>>(Ao, WoutT, bout, gam, bet, out);
}

// Round 5
// 131.371 us; speedup vs baseline: 2.3621x; 1.2027x over previous
//
#include <hip/hip_runtime.h>
#include <math.h>

#define B_ 2
#define L_ 2048
#define D_ 512
#define H_ 8
#define E_ 64
#define CHUNK 32
#define NCH 64                 // L_/CHUNK
#define DEN_EPS_ 1e-5f
#define LN_EPS_ 1e-5f

typedef __bf16 bf16x8 __attribute__((ext_vector_type(8)));
typedef __bf16 bf16x4 __attribute__((ext_vector_type(4)));
typedef float  f32x4  __attribute__((ext_vector_type(4)));

__device__ __forceinline__ float sigm(float x) { return 1.f / (1.f + expf(-x)); }
__device__ __forceinline__ float elu1(float x) { return x > 0.f ? x + 1.f : expf(x); }

// ---------------------------------------------------------------------------
// Both weight transposes in one launch: fp32 [K][N] -> bf16 [N][K]
// ---------------------------------------------------------------------------
__global__ __launch_bounds__(256) void k_transpose_both(
    const float* __restrict__ W1, __bf16* __restrict__ D1,
    const float* __restrict__ W2, __bf16* __restrict__ D2)
{
    const float* src; __bf16* dst; int N;
    if (blockIdx.z == 0) { src = W1; dst = D1; N = 1536; }
    else                 { if (blockIdx.x >= 8) return; src = W2; dst = D2; N = 512; }
    const int K = 512;

    __shared__ __bf16 tile[64][68];
    const int kb = blockIdx.y * 64, nb = blockIdx.x * 64;
    const int t = threadIdx.x;
    const int rr = t >> 4, cc4 = (t & 15) * 4;
#pragma unroll
    for (int p = 0; p < 4; p++) {
        int k = rr + p * 16;
        float4 v = *(const float4*)&src[(size_t)(kb + k) * N + nb + cc4];
        tile[k][cc4 + 0] = (__bf16)v.x;
        tile[k][cc4 + 1] = (__bf16)v.y;
        tile[k][cc4 + 2] = (__bf16)v.z;
        tile[k][cc4 + 3] = (__bf16)v.w;
    }
    __syncthreads();
#pragma unroll
    for (int p = 0; p < 4; p++) {
        int n = rr + p * 16;
        bf16x4 o;
        o[0] = tile[cc4 + 0][n];
        o[1] = tile[cc4 + 1][n];
        o[2] = tile[cc4 + 2][n];
        o[3] = tile[cc4 + 3][n];
        *(bf16x4*)&dst[(size_t)(nb + n) * K + kb + cc4] = o;
    }
}

// ---------------------------------------------------------------------------
// MFMA GEMM 1 (reg-prefetch pipeline): qkv = x @ WqkvT^T + bias,
// featurize, scatter bf16 Q/K/V [B,H,L,E].  128x128 tile, BK=32, 4 waves 2x2
// ---------------------------------------------------------------------------
__global__ __launch_bounds__(256) void k_mfma_qkv(
    const float* __restrict__ X, const __bf16* __restrict__ Bt,
    const float* __restrict__ bias,
    __bf16* __restrict__ Qb, __bf16* __restrict__ Kb, __bf16* __restrict__ Vb)
{
    __shared__ __bf16 Al[128 * 32];
    __shared__ __bf16 Bl[128 * 32];
    const int t = threadIdx.x;
    const int w = t >> 6, lane = t & 63;
    const int wm = w >> 1, wn = w & 1;
    const int ll = lane & 15, quad = lane >> 4;
    const int m0 = blockIdx.y * 128, n0 = blockIdx.x * 128;

    f32x4 acc[4][4] = {};
    const int sr = t >> 2, sk = (t & 3) * 8;

    float4 pa0[2], pa1[2];
    bf16x8 pb[2];
    auto fetch = [&](int k0) {
#pragma unroll
        for (int h2 = 0; h2 < 2; h2++) {
            const float* ap = X + (size_t)(m0 + sr + h2 * 64) * D_ + k0 + sk;
            pa0[h2] = *(const float4*)ap;
            pa1[h2] = *(const float4*)(ap + 4);
        }
        pb[0] = *(const bf16x8*)&Bt[(size_t)(n0 + sr) * D_ + k0 + sk];
        pb[1] = *(const bf16x8*)&Bt[(size_t)(n0 + sr + 64) * D_ + k0 + sk];
    };

    fetch(0);
    for (int k0 = 0; k0 < D_; k0 += 32) {
#pragma unroll
        for (int h2 = 0; h2 < 2; h2++) {
            bf16x8 o;
            o[0] = (__bf16)pa0[h2].x; o[1] = (__bf16)pa0[h2].y;
            o[2] = (__bf16)pa0[h2].z; o[3] = (__bf16)pa0[h2].w;
            o[4] = (__bf16)pa1[h2].x; o[5] = (__bf16)pa1[h2].y;
            o[6] = (__bf16)pa1[h2].z; o[7] = (__bf16)pa1[h2].w;
            *(bf16x8*)&Al[(sr + h2 * 64) * 32 + sk] = o;
        }
        *(bf16x8*)&Bl[sr * 32 + sk]        = pb[0];
        *(bf16x8*)&Bl[(sr + 64) * 32 + sk] = pb[1];
        __syncthreads();
        if (k0 + 32 < D_) fetch(k0 + 32);
#pragma unroll
        for (int im = 0; im < 4; im++) {
            bf16x8 a = *(const bf16x8*)&Al[(wm * 64 + im * 16 + ll) * 32 + quad * 8];
#pragma unroll
            for (int in = 0; in < 4; in++) {
                bf16x8 b = *(const bf16x8*)&Bl[(wn * 64 + in * 16 + ll) * 32 + quad * 8];
                acc[im][in] = __builtin_amdgcn_mfma_f32_16x16x32_bf16(a, b, acc[im][in], 0, 0, 0);
            }
        }
        __syncthreads();
    }

    const int sec = n0 >> 9;   // 0:q 1:k 2:v (uniform per block)
    __bf16* base = (sec == 0 ? Qb : (sec == 1 ? Kb : Vb));
#pragma unroll
    for (int im = 0; im < 4; im++) {
#pragma unroll
        for (int in = 0; in < 4; in++) {
            int n = n0 + wn * 64 + in * 16 + ll;
            int d = n & 511, h = d >> 6, e = d & 63;
            float bv = bias[n];
#pragma unroll
            for (int r = 0; r < 4; r++) {
                int m = m0 + wm * 64 + im * 16 + quad * 4 + r;
                int bb = m >> 11, l = m & 2047;
                float v = acc[im][in][r] + bv;
                if (sec == 0)      v = elu1(v) * 0.125f;
                else if (sec == 1) v = elu1(v);
                base[((size_t)((bb * H_ + h) * L_ + l)) * E_ + e] = (__bf16)v;
            }
        }
    }
}

// ---------------------------------------------------------------------------
// Chunk sums (MFMA): per (b,h,n)  Gt_n = V^T K_w  (stored [f][e], bf16),
//                    g_n[e] = sum_i K_w[i][e] (fp32)
// ---------------------------------------------------------------------------
__global__ __launch_bounds__(256) void k_chunk_g(
    const __bf16* __restrict__ Kb, const __bf16* __restrict__ Vb,
    const float* __restrict__ dl,
    __bf16* __restrict__ Gt, float* __restrict__ gn)
{
    __shared__ __bf16 Kwt[64][40];   // [e][i], weighted
    __shared__ __bf16 Vt[64][40];    // [f][i]
    const int t  = threadIdx.x;
    const int bx = blockIdx.x;
    const int n = bx & 63, h = (bx >> 6) & 7, bb = bx >> 9;
    const int bh = bb * H_ + h;
    const float lam = sigm(dl[h]);

    {   // stage transposed
        int i = t & 31, e0 = (t >> 5) * 8;
        size_t src = ((size_t)bh * L_ + n * CHUNK + i) * E_ + e0;
        float wk = powf(lam, (float)(CHUNK - 1 - i));
        bf16x8 k8 = *(const bf16x8*)&Kb[src];
        bf16x8 v8 = *(const bf16x8*)&Vb[src];
#pragma unroll
        for (int q = 0; q < 8; q++) {
            Kwt[e0 + q][i] = (__bf16)((float)k8[q] * wk);
            Vt[e0 + q][i]  = v8[q];
        }
    }
    __syncthreads();

    const int w = t >> 6, lane = t & 63;
    const int wm = w >> 1, wn = w & 1;
    const int ll = lane & 15, quad = lane >> 4;

    // A-operand rows = f (V), B-operand rows = e (Kw)  ->  C[f][e]
    bf16x8 af[2], bf_[2];
#pragma unroll
    for (int a = 0; a < 2; a++) {
        af[a]  = *(const bf16x8*)&Vt[wm * 32 + a * 16 + ll][quad * 8];
        bf_[a] = *(const bf16x8*)&Kwt[wn * 32 + a * 16 + ll][quad * 8];
    }
    f32x4 acc[2][2] = {};
#pragma unroll
    for (int a = 0; a < 2; a++)
#pragma unroll
        for (int b = 0; b < 2; b++)
            acc[a][b] = __builtin_amdgcn_mfma_f32_16x16x32_bf16(af[a], bf_[b], acc[a][b], 0, 0, 0);

    size_t gbase = ((size_t)bh * NCH + n) * 4096;
#pragma unroll
    for (int a = 0; a < 2; a++)
#pragma unroll
        for (int b = 0; b < 2; b++)
#pragma unroll
            for (int r = 0; r < 4; r++) {
                int f = wm * 32 + a * 16 + quad * 4 + r;
                int e = wn * 32 + b * 16 + ll;
                Gt[gbase + (size_t)f * 64 + e] = (__bf16)acc[a][b][r];
            }

    if (t < 64) {
        float ga = 0.f;
#pragma unroll
        for (int k8 = 0; k8 < 4; k8++) {
            bf16x8 kk = *(const bf16x8*)&Kwt[t][k8 * 8];
#pragma unroll
            for (int q = 0; q < 8; q++) ga += (float)kk[q];
        }
        gn[((size_t)bh * NCH + n) * E_ + t] = ga;
    }
}

// ---------------------------------------------------------------------------
// Scan: block (bh,f); lane = e.  All 64 chunk values loaded to registers
// (independent coalesced loads), then in-register exclusive scan.
// Also z-scan (per (bh, e=f-index)) via weighted Kogge-Stone over lanes=n.
// Emits lam*S^T (bf16, [bh][n][f][e]) and lam*z (fp32).
// ---------------------------------------------------------------------------
__global__ __launch_bounds__(64) void k_scan_par(
    const __bf16* __restrict__ Gt, const float* __restrict__ gn,
    const float* __restrict__ dl,
    __bf16* __restrict__ Sb, float* __restrict__ zl)
{
    const int lane = threadIdx.x;
    const int bh = blockIdx.x >> 6;
    const int j  = blockIdx.x & 63;          // f for S-scan, e for z-scan
    const float lam = sigm(dl[bh & 7]);
    const float dC  = powf(lam, (float)CHUNK);

    const size_t base = ((size_t)bh * NCH) * 4096 + (size_t)j * 64 + lane;

    __bf16 g[NCH];
#pragma unroll
    for (int n = 0; n < NCH; n++) g[n] = Gt[base + (size_t)n * 4096];

    float s = 0.f;
#pragma unroll
    for (int n = 0; n < NCH; n++) {
        Sb[base + (size_t)n * 4096] = (__bf16)(lam * s);
        s = fmaf(dC, s, (float)g[n]);
    }

    // z-scan: lane = n
    float gv = gn[((size_t)bh * NCH + lane) * E_ + j];
    float wf = dC;
#pragma unroll
    for (int k = 1; k < 64; k <<= 1) {
        float up = __shfl_up(gv, k);
        if (lane >= k) gv = fmaf(wf, up, gv);
        wf = wf * wf;
    }
    float zex = __shfl_up(gv, 1);
    if (lane == 0) zex = 0.f;
    zl[((size_t)bh * NCH + lane) * E_ + j] = lam * zex;
}

// ---------------------------------------------------------------------------
// Attention (MFMA): per (b,h,n):
//   A = Qw Kw^T (masked);  O = A V + Qw SbT;  den = rowsum(A) + Qw.zz + eps
//   (Sb/zz carry the lam factor; Sb already transposed [f][e])
// ---------------------------------------------------------------------------
__global__ __launch_bounds__(256) void k_attn(
    const __bf16* __restrict__ Qb, const __bf16* __restrict__ Kb,
    const __bf16* __restrict__ Vb,
    const __bf16* __restrict__ Sb, const float* __restrict__ zl,
    const float* __restrict__ dl, __bf16* __restrict__ Out)
{
    __shared__ __bf16 Qw[32][64];
    __shared__ __bf16 Kw[32][64];
    __shared__ __bf16 Vt[64][40];
    __shared__ __bf16 SbT[64][72];   // [f][e]
    __shared__ __bf16 A1[32][40];
    __shared__ float  den[32];
    __shared__ float  zz[64];

    const int t  = threadIdx.x;
    const int bx = blockIdx.x;
    const int n = bx & 63, h = (bx >> 6) & 7, bb = bx >> 9;
    const int bh = bb * H_ + h;
    const float lam = sigm(dl[h]);

    {   // stage Q,K (weighted), V (transposed)
        int i = t >> 3, e0 = (t & 7) * 8;
        size_t src = ((size_t)bh * L_ + n * CHUNK + i) * E_ + e0;
        float wq = powf(lam, (float)i);
        float wk = powf(lam, -(float)i);
        bf16x8 q8 = *(const bf16x8*)&Qb[src];
        bf16x8 k8 = *(const bf16x8*)&Kb[src];
        bf16x8 v8 = *(const bf16x8*)&Vb[src];
        bf16x8 qo, ko;
#pragma unroll
        for (int q = 0; q < 8; q++) {
            qo[q] = (__bf16)((float)q8[q] * wq);
            ko[q] = (__bf16)((float)k8[q] * wk);
            Vt[e0 + q][i] = v8[q];
        }
        *(bf16x8*)&Qw[i][e0] = qo;
        *(bf16x8*)&Kw[i][e0] = ko;

        // stage lam*S^T (already [f][e]) -> vector copy
        int f = t >> 2, e00 = (t & 3) * 16;
        size_t sbase = ((size_t)bh * NCH + n) * 4096;
        bf16x8 s0 = *(const bf16x8*)&Sb[sbase + (size_t)f * 64 + e00];
        bf16x8 s1 = *(const bf16x8*)&Sb[sbase + (size_t)f * 64 + e00 + 8];
        *(bf16x8*)&SbT[f][e00]     = s0;
        *(bf16x8*)&SbT[f][e00 + 8] = s1;
        if (t < 64) zz[t] = zl[((size_t)bh * NCH + n) * E_ + t];
    }
    __syncthreads();

    const int w = t >> 6, lane = t & 63;
    const int ll = lane & 15, quad = lane >> 4;

    // Phase A: each wave one 16x16 tile of the 32x32 A
    {
        const int wm = w >> 1, wn = w & 1;
        f32x4 accA = {};
#pragma unroll
        for (int ks = 0; ks < 2; ks++) {
            bf16x8 a = *(const bf16x8*)&Qw[wm * 16 + ll][ks * 32 + quad * 8];
            bf16x8 b = *(const bf16x8*)&Kw[wn * 16 + ll][ks * 32 + quad * 8];
            accA = __builtin_amdgcn_mfma_f32_16x16x32_bf16(a, b, accA, 0, 0, 0);
        }
        int j = wn * 16 + ll;
#pragma unroll
        for (int r = 0; r < 4; r++) {
            int i = wm * 16 + quad * 4 + r;
            A1[i][j] = (__bf16)(j <= i ? accA[r] : 0.f);
        }
    }
    __syncthreads();

    // den
    if (t < 32) {
        float rs = 0.f;
#pragma unroll
        for (int k8 = 0; k8 < 4; k8++) {
            bf16x8 aa = *(const bf16x8*)&A1[t][k8 * 8];
#pragma unroll
            for (int q = 0; q < 8; q++) rs += (float)aa[q];
        }
        float qz = 0.f;
#pragma unroll
        for (int e8 = 0; e8 < 8; e8++) {
            bf16x8 qq = *(const bf16x8*)&Qw[t][e8 * 8];
#pragma unroll
            for (int q = 0; q < 8; q++) qz += (float)qq[q] * zz[e8 * 8 + q];
        }
        den[t] = rs + qz + DEN_EPS_;
    }

    // Phase O: wave w owns f-range [w*16, w*16+16)
    const int fw = w * 16;
    f32x4 acc1[2] = {}, acc2[2] = {};
    {
        bf16x8 bV = *(const bf16x8*)&Vt[fw + ll][quad * 8];
#pragma unroll
        for (int im = 0; im < 2; im++) {
            bf16x8 aA = *(const bf16x8*)&A1[im * 16 + ll][quad * 8];
            acc1[im] = __builtin_amdgcn_mfma_f32_16x16x32_bf16(aA, bV, acc1[im], 0, 0, 0);
        }
#pragma unroll
        for (int ks = 0; ks < 2; ks++) {
            bf16x8 bS = *(const bf16x8*)&SbT[fw + ll][ks * 32 + quad * 8];
#pragma unroll
            for (int im = 0; im < 2; im++) {
                bf16x8 aQ = *(const bf16x8*)&Qw[im * 16 + ll][ks * 32 + quad * 8];
                acc2[im] = __builtin_amdgcn_mfma_f32_16x16x32_bf16(aQ, bS, acc2[im], 0, 0, 0);
            }
        }
    }
    __syncthreads();

#pragma unroll
    for (int im = 0; im < 2; im++)
#pragma unroll
        for (int r = 0; r < 4; r++) {
            int i = im * 16 + quad * 4 + r;
            float o = (acc1[im][r] + acc2[im][r]) / den[i];
            Out[((size_t)bb * L_ + n * CHUNK + i) * D_ + h * E_ + fw + ll] = (__bf16)o;
        }
}

// ---------------------------------------------------------------------------
// MFMA GEMM 2 + fused LayerNorm (reg-prefetch): Y = LN(Ao @ WoutT^T + bout)
// Tile 32 rows x 512 cols; 4 waves split N; row stats from regs.
// ---------------------------------------------------------------------------
__global__ __launch_bounds__(256) void k_mfma_out_ln(
    const __bf16* __restrict__ Ab, const __bf16* __restrict__ Bt,
    const float* __restrict__ bias, const float* __restrict__ gam,
    const float* __restrict__ bet, float* __restrict__ Y)
{
    __shared__ __bf16 Al[32 * 32];
    __shared__ __bf16 Bl[512 * 32];
    __shared__ float gaml[512], betl[512], bl[512];
    __shared__ float redS[4][32], redQ[4][32];
    __shared__ float mv[32][2];

    const int t = threadIdx.x;
    const int w = t >> 6, lane = t & 63;
    const int ll = lane & 15, quad = lane >> 4;
    const int m0 = blockIdx.x * 32;

    {   // preload per-column params
        float2 g = *(const float2*)&gam[t * 2];
        float2 b2 = *(const float2*)&bet[t * 2];
        float2 bo = *(const float2*)&bias[t * 2];
        gaml[t * 2] = g.x;  gaml[t * 2 + 1] = g.y;
        betl[t * 2] = b2.x; betl[t * 2 + 1] = b2.y;
        bl[t * 2]   = bo.x; bl[t * 2 + 1]   = bo.y;
    }

    f32x4 acc[2][8] = {};
    const int sr = t >> 2, sk = (t & 3) * 8;

    bf16x8 pA;
    bf16x8 pB[8];
    auto fetch = [&](int k0) {
        if (t < 128)
            pA = *(const bf16x8*)&Ab[(size_t)(m0 + sr) * D_ + k0 + sk];
#pragma unroll
        for (int p = 0; p < 8; p++)
            pB[p] = *(const bf16x8*)&Bt[(size_t)(sr + p * 64) * D_ + k0 + sk];
    };

    fetch(0);
    for (int k0 = 0; k0 < D_; k0 += 32) {
        if (t < 128)
            *(bf16x8*)&Al[sr * 32 + sk] = pA;
#pragma unroll
        for (int p = 0; p < 8; p++)
            *(bf16x8*)&Bl[(sr + p * 64) * 32 + sk] = pB[p];
        __syncthreads();
        if (k0 + 32 < D_) fetch(k0 + 32);
#pragma unroll
        for (int im = 0; im < 2; im++) {
            bf16x8 a = *(const bf16x8*)&Al[(im * 16 + ll) * 32 + quad * 8];
#pragma unroll
            for (int in = 0; in < 8; in++) {
                bf16x8 b = *(const bf16x8*)&Bl[(w * 128 + in * 16 + ll) * 32 + quad * 8];
                acc[im][in] = __builtin_amdgcn_mfma_f32_16x16x32_bf16(a, b, acc[im][in], 0, 0, 0);
            }
        }
        __syncthreads();
    }

    // bias + row-stat partials from registers
    float vals[2][8][4];
    float ps[2][4] = {}, pq[2][4] = {};
#pragma unroll
    for (int im = 0; im < 2; im++)
#pragma unroll
        for (int in = 0; in < 8; in++) {
            int col = w * 128 + in * 16 + ll;
            float bv = bl[col];
#pragma unroll
            for (int r = 0; r < 4; r++) {
                float v = acc[im][in][r] + bv;
                vals[im][in][r] = v;
                ps[im][r] += v;
                pq[im][r] += v * v;
            }
        }
#pragma unroll
    for (int im = 0; im < 2; im++)
#pragma unroll
        for (int r = 0; r < 4; r++) {
            float s = ps[im][r], q = pq[im][r];
            s += __shfl_xor(s, 1); q += __shfl_xor(q, 1);
            s += __shfl_xor(s, 2); q += __shfl_xor(q, 2);
            s += __shfl_xor(s, 4); q += __shfl_xor(q, 4);
            s += __shfl_xor(s, 8); q += __shfl_xor(q, 8);
            if (ll == 0) {
                int row = im * 16 + quad * 4 + r;
                redS[w][row] = s;
                redQ[w][row] = q;
            }
        }
    __syncthreads();
    if (t < 32) {
        float S = redS[0][t] + redS[1][t] + redS[2][t] + redS[3][t];
        float Q = redQ[0][t] + redQ[1][t] + redQ[2][t] + redQ[3][t];
        float mu  = S * (1.f / 512.f);
        float var = Q * (1.f / 512.f) - mu * mu;
        mv[t][0] = mu;
        mv[t][1] = rsqrtf(var + LN_EPS_);
    }
    __syncthreads();
#pragma unroll
    for (int im = 0; im < 2; im++)
#pragma unroll
        for (int r = 0; r < 4; r++) {
            int row = im * 16 + quad * 4 + r;
            float mu = mv[row][0], rs = mv[row][1];
#pragma unroll
            for (int in = 0; in < 8; in++) {
                int col = w * 128 + in * 16 + ll;
                Y[(size_t)(m0 + row) * D_ + col] =
                    (vals[im][in][r] - mu) * rs * gaml[col] + betl[col];
            }
        }
}

// ---------------------------------------------------------------------------
extern "C" void kernel_launch(void* const* d_in, const int* in_sizes, int n_in,
                              void* d_out, int out_size, void* d_ws, size_t ws_size,
                              hipStream_t stream)
{
    const float* x    = (const float*)d_in[0];
    const float* Wqkv = (const float*)d_in[1];
    const float* bqkv = (const float*)d_in[2];
    const float* Wout = (const float*)d_in[3];
    const float* bout = (const float*)d_in[4];
    const float* gam  = (const float*)d_in[5];
    const float* bet  = (const float*)d_in[6];
    const float* dl   = (const float*)d_in[7];
    float* out = (float*)d_out;

    const size_t NBHLE = (size_t)B_ * H_ * L_ * E_;       // 2,097,152
    const size_t NG    = (size_t)B_ * H_ * NCH * E_ * E_; // 4,194,304
    const size_t Ng    = (size_t)B_ * H_ * NCH * E_;      // 65,536

    char* p = (char*)d_ws;
    __bf16* Gt  = (__bf16*)p;    p += NG * 2;
    __bf16* Sb  = (__bf16*)p;    p += NG * 2;
    float*  gn  = (float*)p;     p += Ng * 4;
    float*  zl  = (float*)p;     p += Ng * 4;
    __bf16* Qb  = (__bf16*)p;    p += NBHLE * 2;
    __bf16* Kb  = (__bf16*)p;    p += NBHLE * 2;
    __bf16* Vb  = (__bf16*)p;    p += NBHLE * 2;
    __bf16* WqkvT = (__bf16*)p;  p += (size_t)1536 * 512 * 2;
    __bf16* WoutT = (__bf16*)p;  p += (size_t)512 * 512 * 2;
    __bf16* Ao    = (__bf16*)p;  p += NBHLE * 2;               // [4096][512]

    dim3 blk(256);
    k_transpose_both<<<dim3(24, 8, 2), blk, 0, stream>>>(Wqkv, WqkvT, Wout, WoutT);
    k_mfma_qkv      <<<dim3(12, 32),   blk, 0, stream>>>(x, WqkvT, bqkv, Qb, Kb, Vb);
    k_chunk_g       <<<dim3(1024),     blk, 0, stream>>>(Kb, Vb, dl, Gt, gn);
    k_scan_par      <<<dim3(1024),     dim3(64), 0, stream>>>(Gt, gn, dl, Sb, zl);
    k_attn          <<<dim3(1024),     blk, 0, stream>>>(Qb, Kb, Vb, Sb, zl, dl, Ao);
    k_mfma_out_ln   <<<dim3(128),      blk, 0, stream>>>(Ao, WoutT, bout, gam, bet, out);
}